// Round 1
// baseline (647.062 us; speedup 1.0000x reference)
//
#include <hip/hip_runtime.h>
#include <math.h>

// ContextEncoder: B=512, L=10, H=256, D=512.
// Decomposition:
//  P/Q GEMM: PQ[B*L][1024] = utt @ [a_w1_i | a_w1_j | s_w1_i | s_w1_j]^T
//  BN1 stats closed-form from P/Q moments (no L^2 pass).
//  fused_layer2: z2 = relu/tanh(bn1(P_i+Q_j+b1)) @ W2^T + b2 over 51200 rows,
//    accumulating BN2 sum/sumsq per i-channel, writing only anchor rows.
//  postproc: bn2+act+3 dots, aij/sij/wij, softmax, message, h0.
//  GRU: two small GEMMs + elementwise.

__device__ __forceinline__ float softplusf(float x) {
  return x > 0.f ? x + log1pf(expf(-x)) : log1pf(expf(x));
}
__device__ __forceinline__ float wred64(float v) {
#pragma unroll
  for (int o = 32; o > 0; o >>= 1) v += __shfl_down(v, o);
  return v;
}

// ---------------- weight prep (transposes) ----------------
__global__ __launch_bounds__(256) void prep_weights(
    const float* __restrict__ a_w1, const float* __restrict__ s_w1,
    const float* __restrict__ a_w2, const float* __restrict__ s_w2,
    const float* __restrict__ gru_wi, const float* __restrict__ gru_wh,
    float* __restrict__ WcatT, float* __restrict__ W2Ta, float* __restrict__ W2Ts,
    float* __restrict__ wiT, float* __restrict__ whT) {
  const int total = 524288 + 65536 + 65536 + 393216 + 196608;
  for (int idx = blockIdx.x * 256 + threadIdx.x; idx < total; idx += gridDim.x * 256) {
    int id = idx;
    if (id < 524288) {  // WcatT[d][c], d<512, c<1024
      int d = id >> 10, c = id & 1023;
      float v;
      if (c < 256)       v = a_w1[c * 1024 + d];
      else if (c < 512)  v = a_w1[(c - 256) * 1024 + 512 + d];
      else if (c < 768)  v = s_w1[(c - 512) * 1024 + d];
      else               v = s_w1[(c - 768) * 1024 + 512 + d];
      WcatT[id] = v; continue;
    }
    id -= 524288;
    if (id < 65536) { int k = id >> 8, n = id & 255; W2Ta[id] = a_w2[n * 256 + k]; continue; }
    id -= 65536;
    if (id < 65536) { int k = id >> 8, n = id & 255; W2Ts[id] = s_w2[n * 256 + k]; continue; }
    id -= 65536;
    if (id < 393216) { int k = id / 768, o = id - (id / 768) * 768; wiT[id] = gru_wi[o * 512 + k]; continue; }
    id -= 393216;
    { int k = id / 768, o = id - (id / 768) * 768; whT[id] = gru_wh[o * 256 + k]; }
  }
}

// ---------------- generic fp32 tiled GEMM: C[M][N] = A[M][K] @ Wt[K][N] (+bias) ----------------
__global__ __launch_bounds__(256) void gemm64(const float* __restrict__ A,
                                              const float* __restrict__ Wt,
                                              float* __restrict__ C,
                                              const float* __restrict__ bias,
                                              int M, int N, int K) {
  __shared__ float As[16][68];
  __shared__ float Bs[16][68];
  int t = threadIdx.x;
  int bm = blockIdx.x * 64, bn = blockIdx.y * 64;
  int tx = t & 15, ty = t >> 4;
  float acc[4][4] = {};
  for (int kc = 0; kc < K; kc += 16) {
#pragma unroll
    for (int s = 0; s < 4; ++s) {
      int idx = t + s * 256;
      int k = idx & 15, m = idx >> 4;
      As[k][m] = A[(bm + m) * K + kc + k];
    }
#pragma unroll
    for (int s = 0; s < 4; ++s) {
      int idx = t + s * 256;
      int n = idx & 63, k = idx >> 6;
      Bs[k][n] = Wt[(kc + k) * N + bn + n];
    }
    __syncthreads();
#pragma unroll
    for (int k = 0; k < 16; ++k) {
      float4 a4 = *(const float4*)&As[k][ty * 4];
      float4 b4 = *(const float4*)&Bs[k][tx * 4];
      float av[4] = {a4.x, a4.y, a4.z, a4.w};
      float bv[4] = {b4.x, b4.y, b4.z, b4.w};
#pragma unroll
      for (int mi = 0; mi < 4; ++mi)
#pragma unroll
        for (int ni = 0; ni < 4; ++ni) acc[mi][ni] += av[mi] * bv[ni];
    }
    __syncthreads();
  }
#pragma unroll
  for (int mi = 0; mi < 4; ++mi) {
    int row = bm + ty * 4 + mi;
    int col = bn + tx * 4;
    float4 o;
    o.x = acc[mi][0]; o.y = acc[mi][1]; o.z = acc[mi][2]; o.w = acc[mi][3];
    if (bias) { o.x += bias[col]; o.y += bias[col + 1]; o.z += bias[col + 2]; o.w += bias[col + 3]; }
    *(float4*)&C[row * N + col] = o;
  }
}

// ---------------- Q moments: Qbar[b][h], SQ, SQ2 (both branches) ----------------
__global__ __launch_bounds__(256) void qstats_kernel(const float* __restrict__ PQ,
                                                     float* __restrict__ Qbar_a,
                                                     float* __restrict__ Qbar_s,
                                                     float* __restrict__ ST) {
  int b = blockIdx.x, t = threadIdx.x;
  float sa = 0, sa2 = 0, ss = 0, ss2 = 0;
#pragma unroll
  for (int j = 0; j < 10; ++j) {
    float qa = PQ[(b * 10 + j) * 1024 + 256 + t];
    float qs = PQ[(b * 10 + j) * 1024 + 768 + t];
    sa += qa; sa2 += qa * qa; ss += qs; ss2 += qs * qs;
  }
  Qbar_a[b * 256 + t] = sa * 0.1f;
  Qbar_s[b * 256 + t] = ss * 0.1f;
  sa = wred64(sa); sa2 = wred64(sa2); ss = wred64(ss); ss2 = wred64(ss2);
  if ((t & 63) == 0) {
    atomicAdd(&ST[0], sa); atomicAdd(&ST[1], sa2);
    atomicAdd(&ST[2], ss); atomicAdd(&ST[3], ss2);
  }
}

// ---------------- P moments per i-channel ----------------
__global__ __launch_bounds__(256) void pstats_kernel(const float* __restrict__ PQ,
                                                     const float* __restrict__ Qbar_a,
                                                     const float* __restrict__ Qbar_s,
                                                     const float* __restrict__ a_b1,
                                                     const float* __restrict__ s_b1,
                                                     float* __restrict__ ST) {
  int i = blockIdx.x, t = threadIdx.x;
  int b0 = blockIdx.y * 64;
  float ab1 = a_b1[t], sb1 = s_b1[t];
  float s1a = 0, s2a = 0, s3a = 0, s1s = 0, s2s = 0, s3s = 0;
  for (int b = b0; b < b0 + 64; ++b) {
    float pa = PQ[(b * 10 + i) * 1024 + t];
    float aa = pa + ab1;
    s1a += pa; s2a += aa * aa; s3a += aa * Qbar_a[b * 256 + t];
    float ps = PQ[(b * 10 + i) * 1024 + 512 + t];
    float as = ps + sb1;
    s1s += ps; s2s += as * as; s3s += as * Qbar_s[b * 256 + t];
  }
  s1a = wred64(s1a); s2a = wred64(s2a); s3a = wred64(s3a);
  s1s = wred64(s1s); s2s = wred64(s2s); s3s = wred64(s3s);
  if ((t & 63) == 0) {
    atomicAdd(&ST[4 + i * 3 + 0], s1a); atomicAdd(&ST[4 + i * 3 + 1], s2a); atomicAdd(&ST[4 + i * 3 + 2], s3a);
    atomicAdd(&ST[34 + i * 3 + 0], s1s); atomicAdd(&ST[34 + i * 3 + 1], s2s); atomicAdd(&ST[34 + i * 3 + 2], s3s);
  }
}

// ---------------- BN1 closed-form finalize ----------------
__global__ void finalize_bn1(const float* __restrict__ a_b1, const float* __restrict__ s_b1,
                             const float* __restrict__ a_g1, const float* __restrict__ a_be1,
                             const float* __restrict__ s_g1, const float* __restrict__ s_be1,
                             float* __restrict__ ST) {
  int t = threadIdx.x;
  if (t >= 20) return;
  int br = t / 10, i = t % 10;
  const float* b1 = br ? s_b1 : a_b1;
  float bsum = 0;
  for (int h = 0; h < 256; ++h) bsum += b1[h];
  float meanb1 = bsum * (1.f / 256.f);
  const float invBH = 1.f / (512.f * 256.f);
  const float invBLH = 1.f / (512.f * 10.f * 256.f);
  int base = (br ? 34 : 4) + i * 3;
  float SP = ST[base + 0], SA2 = ST[base + 1], SPQ = ST[base + 2];
  float SQ = ST[br ? 2 : 0], SQ2 = ST[br ? 3 : 1];
  float mean = SP * invBH + meanb1 + SQ * invBLH;
  float Ez2 = SA2 * invBH + 2.f * SPQ * invBH + SQ2 * invBLH;
  float var = Ez2 - mean * mean;
  float g = br ? s_g1[i] : a_g1[i];
  float be = br ? s_be1[i] : a_be1[i];
  float sc = g / sqrtf(var + 1e-5f);
  ST[64 + br * 20 + i] = sc;
  ST[64 + br * 20 + 10 + i] = be - mean * sc;
}

// ---------------- fused layer2: h1 on-the-fly, GEMM, BN2 stats, anchor-row writes ----------------
template <int ACT>  // 0=relu, 1=tanh
__global__ __launch_bounds__(256) void fused_layer2(
    const float* __restrict__ PQ, int p_off, int q_off,
    const float* __restrict__ b1, const float* __restrict__ ST, int sc_off,
    const float* __restrict__ W2T, const float* __restrict__ b2,
    const int* __restrict__ cl, float* __restrict__ Z2out,
    float* __restrict__ sumP, float* __restrict__ sumsqP) {
  __shared__ float As[16][68];
  __shared__ float Bs[16][68];
  __shared__ float binS[10], binQ[10];
  int t = threadIdx.x;
  int rowBase = blockIdx.x * 64;
  int bn = blockIdx.y * 64;
  int tx = t & 15, ty = t >> 4;
  int kS = t & 15, mS0 = t >> 4;
  int pRow[4], qRow[4];
  float sc1v[4], sh1v[4];
#pragma unroll
  for (int s = 0; s < 4; ++s) {
    int m = mS0 + s * 16;
    int r = rowBase + m;
    int bb = r / 100;
    int rem = r - bb * 100;
    int ii = rem / 10;
    int jj = rem - ii * 10;
    pRow[s] = (bb * 10 + ii) * 1024 + p_off;
    qRow[s] = (bb * 10 + jj) * 1024 + q_off;
    sc1v[s] = ST[sc_off + ii];
    sh1v[s] = ST[sc_off + 10 + ii];
  }
  if (t < 10) { binS[t] = 0.f; binQ[t] = 0.f; }
  float acc[4][4] = {};
  for (int kc = 0; kc < 256; kc += 16) {
    float b1v = b1[kc + kS];
#pragma unroll
    for (int s = 0; s < 4; ++s) {
      float p = PQ[pRow[s] + kc + kS];
      float q = PQ[qRow[s] + kc + kS];
      float z = (p + q + b1v) * sc1v[s] + sh1v[s];
      As[kS][mS0 + s * 16] = ACT ? tanhf(z) : fmaxf(z, 0.f);
    }
#pragma unroll
    for (int s = 0; s < 4; ++s) {
      int idx = t + s * 256;
      int n = idx & 63, k = idx >> 6;
      Bs[k][n] = W2T[(kc + k) * 256 + bn + n];
    }
    __syncthreads();
#pragma unroll
    for (int k = 0; k < 16; ++k) {
      float4 a4 = *(const float4*)&As[k][ty * 4];
      float4 b4 = *(const float4*)&Bs[k][tx * 4];
      float av[4] = {a4.x, a4.y, a4.z, a4.w};
      float bv[4] = {b4.x, b4.y, b4.z, b4.w};
#pragma unroll
      for (int mi = 0; mi < 4; ++mi)
#pragma unroll
        for (int ni = 0; ni < 4; ++ni) acc[mi][ni] += av[mi] * bv[ni];
    }
    __syncthreads();
  }
  float b2v[4];
#pragma unroll
  for (int ni = 0; ni < 4; ++ni) b2v[ni] = b2[bn + tx * 4 + ni];
#pragma unroll
  for (int mi = 0; mi < 4; ++mi) {
    int m = ty * 4 + mi;
    int r = rowBase + m;
    int bb = r / 100;
    int rem = r - bb * 100;
    int ii = rem / 10;
    int jj = rem - ii * 10;
    float z[4];
    float s = 0.f, q = 0.f;
#pragma unroll
    for (int ni = 0; ni < 4; ++ni) {
      z[ni] = acc[mi][ni] + b2v[ni];
      s += z[ni];
      q += z[ni] * z[ni];
    }
    atomicAdd(&binS[ii], s);
    atomicAdd(&binQ[ii], q);
    if (ii == cl[bb] - 1) {
      float4 zz; zz.x = z[0]; zz.y = z[1]; zz.z = z[2]; zz.w = z[3];
      *(float4*)&Z2out[(bb * 10 + jj) * 256 + bn + tx * 4] = zz;
    }
  }
  __syncthreads();
  if (t < 10) {
    atomicAdd(&sumP[t], binS[t]);
    atomicAdd(&sumsqP[t], binQ[t]);
  }
}

// ---------------- BN2 finalize ----------------
__global__ void finalize_bn2(const float* __restrict__ a_g2, const float* __restrict__ a_be2,
                             const float* __restrict__ s_g2, const float* __restrict__ s_be2,
                             float* __restrict__ ST) {
  int t = threadIdx.x;
  if (t >= 20) return;
  int br = t / 10, i = t % 10;
  const float invN = 1.f / (512.f * 10.f * 256.f);
  float m = ST[104 + br * 20 + i] * invN;
  float v = ST[104 + br * 20 + 10 + i] * invN - m * m;
  float g = br ? s_g2[i] : a_g2[i];
  float be = br ? s_be2[i] : a_be2[i];
  float sc = g / sqrtf(v + 1e-5f);
  ST[144 + br * 20 + i] = sc;
  ST[144 + br * 20 + 10 + i] = be - m * sc;
}

// ---------------- postproc: bn2+act+dots, aij/sij/wij, softmax, message, h0 ----------------
__global__ __launch_bounds__(256) void postproc_kernel(
    const float* __restrict__ Z2a, const float* __restrict__ Z2s, const float* __restrict__ ST,
    const float* __restrict__ a_w3, const float* __restrict__ a_b3,
    const float* __restrict__ mu_w, const float* __restrict__ mu_b,
    const float* __restrict__ sg_w, const float* __restrict__ sg_b,
    const float* __restrict__ aij_eps, const float* __restrict__ sij_eps,
    const int* __restrict__ cl, const float* __restrict__ utt,
    float* __restrict__ message, float* __restrict__ h0out) {
  int b = blockIdx.x, t = threadIdx.x;
  int a = cl[b] - 1;
  float sc2a = ST[144 + a], sh2a = ST[154 + a];
  float sc2s = ST[164 + a], sh2s = ST[174 + a];
  float w3 = a_w3[t], mw = mu_w[t], sw = sg_w[t];
  __shared__ float red[30];
  if (t < 30) red[t] = 0.f;
  __syncthreads();
#pragma unroll
  for (int j = 0; j < 10; ++j) {
    float za = Z2a[(b * 10 + j) * 256 + t];
    float va = fmaxf(za * sc2a + sh2a, 0.f);
    float zs = Z2s[(b * 10 + j) * 256 + t];
    float vs = tanhf(zs * sc2s + sh2s);
    float pa = wred64(va * w3);
    float pm = wred64(vs * mw);
    float ps = wred64(vs * sw);
    if ((t & 63) == 0) {
      atomicAdd(&red[j], pa);
      atomicAdd(&red[10 + j], pm);
      atomicAdd(&red[20 + j], ps);
    }
  }
  __syncthreads();
  __shared__ float pw[10];
  __shared__ float wijs[16];
  if (t < 10) {
    int j = t;
    float amij = red[j] + a_b3[0];
    float amu = softplusf(amij) + 0.01f;
    float astd = sqrtf(softplusf((1.f - amu) * amu) + 0.01f);
    float ae = aij_eps[b * 100 + a * 10 + j];
    float aij = softplusf(ae * astd + amu) + 0.01f;
    float smu = red[10 + j] + mu_b[0];
    float ssg = red[20 + j] + sg_b[0];
    float se = sij_eps[b * 100 + a * 10 + j];
    float sij = se * sqrtf(aij * ssg * ssg) + aij * smu;
    wijs[j] = aij * sij;
  }
  __syncthreads();
  if (t == 0) {
    float mx = -1e30f;
    for (int j = 0; j < a; ++j) mx = fmaxf(mx, wijs[j]);
    float e[10];
    float den = 0.f;
    for (int j = 0; j < a; ++j) { e[j] = expf(wijs[j] - mx); den += e[j]; }
    for (int j = 0; j < 10; ++j) pw[j] = (j < a) ? e[j] / den : 0.f;
  }
  __syncthreads();
#pragma unroll
  for (int dd = 0; dd < 2; ++dd) {
    int d = t + dd * 256;
    float mv = 0.f;
#pragma unroll
    for (int j = 0; j < 10; ++j) mv += pw[j] * utt[(b * 10 + j) * 512 + d];
    message[b * 512 + d] = mv;
  }
  float u1 = utt[(b * 10 + a) * 512 + t];
  float u2 = utt[(b * 10 + a) * 512 + 256 + t];
  h0out[b * 256 + t] = u1 + u2;
}

// ---------------- GRU elementwise ----------------
__global__ __launch_bounds__(256) void gru_final(const float* __restrict__ gi,
                                                 const float* __restrict__ gh,
                                                 const float* __restrict__ h0,
                                                 float* __restrict__ out) {
  int idx = blockIdx.x * 256 + threadIdx.x;
  int b = idx >> 8, h = idx & 255;
  float ir = gi[b * 768 + h], iz = gi[b * 768 + 256 + h], inn = gi[b * 768 + 512 + h];
  float hr = gh[b * 768 + h], hz = gh[b * 768 + 256 + h], hn = gh[b * 768 + 512 + h];
  float r = 1.f / (1.f + expf(-(ir + hr)));
  float z = 1.f / (1.f + expf(-(iz + hz)));
  float n = tanhf(inn + r * hn);
  out[idx] = (1.f - z) * n + z * h0[b * 256 + h];
}

extern "C" void kernel_launch(void* const* d_in, const int* in_sizes, int n_in,
                              void* d_out, int out_size, void* d_ws, size_t ws_size,
                              hipStream_t stream) {
  const float* utt = (const float*)d_in[0];
  const float* aij_eps = (const float*)d_in[1];
  const float* sij_eps = (const float*)d_in[2];
  const int* cl = (const int*)d_in[3];
  const float* a_w1 = (const float*)d_in[4];
  const float* a_b1 = (const float*)d_in[5];
  const float* a_g1 = (const float*)d_in[6];
  const float* a_be1 = (const float*)d_in[7];
  const float* a_w2 = (const float*)d_in[8];
  const float* a_b2 = (const float*)d_in[9];
  const float* a_g2 = (const float*)d_in[10];
  const float* a_be2 = (const float*)d_in[11];
  const float* a_w3 = (const float*)d_in[12];
  const float* a_b3 = (const float*)d_in[13];
  const float* s_w1 = (const float*)d_in[14];
  const float* s_b1 = (const float*)d_in[15];
  const float* s_g1 = (const float*)d_in[16];
  const float* s_be1 = (const float*)d_in[17];
  const float* s_w2 = (const float*)d_in[18];
  const float* s_b2 = (const float*)d_in[19];
  const float* s_g2 = (const float*)d_in[20];
  const float* s_be2 = (const float*)d_in[21];
  const float* mu_w = (const float*)d_in[22];
  const float* mu_b = (const float*)d_in[23];
  const float* sg_w = (const float*)d_in[24];
  const float* sg_b = (const float*)d_in[25];
  const float* gru_wi = (const float*)d_in[26];
  const float* gru_wh = (const float*)d_in[27];
  const float* gru_bi = (const float*)d_in[28];
  const float* gru_bh = (const float*)d_in[29];

  float* ws = (float*)d_ws;
  float* ST = ws;                   // 256
  float* WcatT = ws + 256;          // 524288
  float* W2Ta = WcatT + 524288;     // 65536
  float* W2Ts = W2Ta + 65536;       // 65536
  float* wiT = W2Ts + 65536;        // 393216
  float* whT = wiT + 393216;        // 196608
  float* PQ = whT + 196608;         // 5242880
  float* Qba = PQ + 5242880;        // 131072
  float* Qbs = Qba + 131072;        // 131072
  float* Z2a = Qbs + 131072;        // 1310720
  float* Z2s = Z2a + 1310720;       // 1310720
  // msg/h0/gi/gh alias the PQ region (PQ dead after fused_layer2)
  float* msg = PQ;                  // 262144
  float* h0 = PQ + 262144;          // 131072
  float* gi = PQ + 393216;          // 393216
  float* gh = PQ + 786432;          // 393216

  hipMemsetAsync(ST, 0, 256 * sizeof(float), stream);
  prep_weights<<<512, 256, 0, stream>>>(a_w1, s_w1, a_w2, s_w2, gru_wi, gru_wh,
                                        WcatT, W2Ta, W2Ts, wiT, whT);
  gemm64<<<dim3(80, 16), 256, 0, stream>>>(utt, WcatT, PQ, nullptr, 5120, 1024, 512);
  qstats_kernel<<<512, 256, 0, stream>>>(PQ, Qba, Qbs, ST);
  pstats_kernel<<<dim3(10, 8), 256, 0, stream>>>(PQ, Qba, Qbs, a_b1, s_b1, ST);
  finalize_bn1<<<1, 64, 0, stream>>>(a_b1, s_b1, a_g1, a_be1, s_g1, s_be1, ST);
  fused_layer2<0><<<dim3(800, 4), 256, 0, stream>>>(PQ, 0, 256, a_b1, ST, 64, W2Ta, a_b2,
                                                    cl, Z2a, ST + 104, ST + 114);
  fused_layer2<1><<<dim3(800, 4), 256, 0, stream>>>(PQ, 512, 768, s_b1, ST, 84, W2Ts, s_b2,
                                                    cl, Z2s, ST + 124, ST + 134);
  finalize_bn2<<<1, 32, 0, stream>>>(a_g2, a_be2, s_g2, s_be2, ST);
  postproc_kernel<<<512, 256, 0, stream>>>(Z2a, Z2s, ST, a_w3, a_b3, mu_w, mu_b, sg_w, sg_b,
                                           aij_eps, sij_eps, cl, utt, msg, h0);
  gemm64<<<dim3(8, 12), 256, 0, stream>>>(msg, wiT, gi, gru_bi, 512, 768, 512);
  gemm64<<<dim3(8, 12), 256, 0, stream>>>(h0, whT, gh, gru_bh, 512, 768, 256);
  gru_final<<<512, 256, 0, stream>>>(gi, gh, h0, (float*)d_out);
}

// Round 2
// 379.095 us; speedup vs baseline: 1.7069x; 1.7069x over previous
//
#include <hip/hip_runtime.h>
#include <math.h>

// ContextEncoder: B=512, L=10, H=256, D=512.
//  prep: transposes + bf16 conversions (utt, Wcat, W2a, W2s).
//  gemm_pq_mfma: PQ[5120][1024] = utt_bf @ Wcat_bf^T (MFMA bf16, fp32 out).
//  qstats/pstats + finalize_bn1: BN1 closed-form (no L^2 pass).
//  fused_layer2_mfma: h1 tile (bf16, LDS) -> MFMA z2 -> BN2 stats + anchor rows.
//  finalize_bn2, postproc, GRU (fp32 gemm64 + elementwise).

typedef __attribute__((ext_vector_type(8))) short short8;
typedef __attribute__((ext_vector_type(4))) float f32x4;

__device__ __forceinline__ float softplusf(float x) {
  return x > 0.f ? x + log1pf(expf(-x)) : log1pf(expf(x));
}
__device__ __forceinline__ float wred64(float v) {
#pragma unroll
  for (int o = 32; o > 0; o >>= 1) v += __shfl_down(v, o);
  return v;
}
__device__ __forceinline__ unsigned short f2bf(float f) {
  unsigned int u = __float_as_uint(f);
  u += 0x7fffu + ((u >> 16) & 1u);
  return (unsigned short)(u >> 16);
}

// ---------------- prep: fp32 transposes + bf16 conversions ----------------
__global__ __launch_bounds__(256) void prep_weights(
    const float* __restrict__ utt,
    const float* __restrict__ a_w1, const float* __restrict__ s_w1,
    const float* __restrict__ a_w2, const float* __restrict__ s_w2,
    const float* __restrict__ gru_wi, const float* __restrict__ gru_wh,
    float* __restrict__ wiT, float* __restrict__ whT,
    unsigned short* __restrict__ uttbf, unsigned short* __restrict__ Wcatbf,
    unsigned short* __restrict__ W2abf, unsigned short* __restrict__ W2sbf) {
  const int total = 393216 + 196608 + 2621440 + 524288 + 65536 + 65536;
  for (int idx = blockIdx.x * 256 + threadIdx.x; idx < total; idx += gridDim.x * 256) {
    int id = idx;
    if (id < 393216) { int k = id / 768, o = id - k * 768; wiT[id] = gru_wi[o * 512 + k]; continue; }
    id -= 393216;
    if (id < 196608) { int k = id / 768, o = id - k * 768; whT[id] = gru_wh[o * 256 + k]; continue; }
    id -= 196608;
    if (id < 2621440) { uttbf[id] = f2bf(utt[id]); continue; }
    id -= 2621440;
    if (id < 524288) {  // Wcatbf[c][k], c<1024, k<512
      int c = id >> 9, k = id & 511;
      float v;
      if (c < 256)       v = a_w1[c * 1024 + k];
      else if (c < 512)  v = a_w1[(c - 256) * 1024 + 512 + k];
      else if (c < 768)  v = s_w1[(c - 512) * 1024 + k];
      else               v = s_w1[(c - 768) * 1024 + 512 + k];
      Wcatbf[id] = f2bf(v); continue;
    }
    id -= 524288;
    if (id < 65536) { W2abf[id] = f2bf(a_w2[id]); continue; }
    id -= 65536;
    W2sbf[id] = f2bf(s_w2[id]);
  }
}

// ---------------- PQ GEMM via MFMA: C[5120][1024] = A[5120][512] @ Bw[1024][512]^T ----------------
__global__ __launch_bounds__(256) void gemm_pq_mfma(
    const unsigned short* __restrict__ A, const unsigned short* __restrict__ Bw,
    float* __restrict__ C) {
  int t = threadIdx.x;
  int w = t >> 6, l = t & 63, li = l & 15, lg = l >> 4;
  int rowBase = blockIdx.x * 64;
  int colBase = blockIdx.y * 256 + w * 64;
  f32x4 acc[4][4] = {};
  const unsigned short* Arow[4];
  const unsigned short* Brow[4];
#pragma unroll
  for (int fr = 0; fr < 4; ++fr) Arow[fr] = A + (rowBase + fr * 16 + li) * 512;
#pragma unroll
  for (int cf = 0; cf < 4; ++cf) Brow[cf] = Bw + (colBase + cf * 16 + li) * 512;
  for (int ks = 0; ks < 16; ++ks) {
    int ka = ks * 32 + lg * 8;
    short8 afr[4], bfr[4];
#pragma unroll
    for (int fr = 0; fr < 4; ++fr) afr[fr] = *(const short8*)&Arow[fr][ka];
#pragma unroll
    for (int cf = 0; cf < 4; ++cf) bfr[cf] = *(const short8*)&Brow[cf][ka];
#pragma unroll
    for (int fr = 0; fr < 4; ++fr)
#pragma unroll
      for (int cf = 0; cf < 4; ++cf)
        acc[fr][cf] = __builtin_amdgcn_mfma_f32_16x16x32_bf16(afr[fr], bfr[cf], acc[fr][cf], 0, 0, 0);
  }
#pragma unroll
  for (int fr = 0; fr < 4; ++fr)
#pragma unroll
    for (int reg = 0; reg < 4; ++reg) {
      int r = rowBase + fr * 16 + lg * 4 + reg;
      float* crow = C + r * 1024 + colBase + li;
#pragma unroll
      for (int cf = 0; cf < 4; ++cf) crow[cf * 16] = acc[fr][cf][reg];
    }
}

// ---------------- Q moments ----------------
__global__ __launch_bounds__(256) void qstats_kernel(const float* __restrict__ PQ,
                                                     float* __restrict__ Qbar_a,
                                                     float* __restrict__ Qbar_s,
                                                     float* __restrict__ ST) {
  int b = blockIdx.x, t = threadIdx.x;
  float sa = 0, sa2 = 0, ss = 0, ss2 = 0;
#pragma unroll
  for (int j = 0; j < 10; ++j) {
    float qa = PQ[(b * 10 + j) * 1024 + 256 + t];
    float qs = PQ[(b * 10 + j) * 1024 + 768 + t];
    sa += qa; sa2 += qa * qa; ss += qs; ss2 += qs * qs;
  }
  Qbar_a[b * 256 + t] = sa * 0.1f;
  Qbar_s[b * 256 + t] = ss * 0.1f;
  sa = wred64(sa); sa2 = wred64(sa2); ss = wred64(ss); ss2 = wred64(ss2);
  if ((t & 63) == 0) {
    atomicAdd(&ST[0], sa); atomicAdd(&ST[1], sa2);
    atomicAdd(&ST[2], ss); atomicAdd(&ST[3], ss2);
  }
}

// ---------------- P moments per i-channel ----------------
__global__ __launch_bounds__(256) void pstats_kernel(const float* __restrict__ PQ,
                                                     const float* __restrict__ Qbar_a,
                                                     const float* __restrict__ Qbar_s,
                                                     const float* __restrict__ a_b1,
                                                     const float* __restrict__ s_b1,
                                                     float* __restrict__ ST) {
  int i = blockIdx.x, t = threadIdx.x;
  int b0 = blockIdx.y * 64;
  float ab1 = a_b1[t], sb1 = s_b1[t];
  float s1a = 0, s2a = 0, s3a = 0, s1s = 0, s2s = 0, s3s = 0;
  for (int b = b0; b < b0 + 64; ++b) {
    float pa = PQ[(b * 10 + i) * 1024 + t];
    float aa = pa + ab1;
    s1a += pa; s2a += aa * aa; s3a += aa * Qbar_a[b * 256 + t];
    float ps = PQ[(b * 10 + i) * 1024 + 512 + t];
    float as = ps + sb1;
    s1s += ps; s2s += as * as; s3s += as * Qbar_s[b * 256 + t];
  }
  s1a = wred64(s1a); s2a = wred64(s2a); s3a = wred64(s3a);
  s1s = wred64(s1s); s2s = wred64(s2s); s3s = wred64(s3s);
  if ((t & 63) == 0) {
    atomicAdd(&ST[4 + i * 3 + 0], s1a); atomicAdd(&ST[4 + i * 3 + 1], s2a); atomicAdd(&ST[4 + i * 3 + 2], s3a);
    atomicAdd(&ST[34 + i * 3 + 0], s1s); atomicAdd(&ST[34 + i * 3 + 1], s2s); atomicAdd(&ST[34 + i * 3 + 2], s3s);
  }
}

// ---------------- BN1 closed-form finalize ----------------
__global__ void finalize_bn1(const float* __restrict__ a_b1, const float* __restrict__ s_b1,
                             const float* __restrict__ a_g1, const float* __restrict__ a_be1,
                             const float* __restrict__ s_g1, const float* __restrict__ s_be1,
                             float* __restrict__ ST) {
  int t = threadIdx.x;
  if (t >= 20) return;
  int br = t / 10, i = t % 10;
  const float* b1 = br ? s_b1 : a_b1;
  float bsum = 0;
  for (int h = 0; h < 256; ++h) bsum += b1[h];
  float meanb1 = bsum * (1.f / 256.f);
  const float invBH = 1.f / (512.f * 256.f);
  const float invBLH = 1.f / (512.f * 10.f * 256.f);
  int base = (br ? 34 : 4) + i * 3;
  float SP = ST[base + 0], SA2 = ST[base + 1], SPQ = ST[base + 2];
  float SQ = ST[br ? 2 : 0], SQ2 = ST[br ? 3 : 1];
  float mean = SP * invBH + meanb1 + SQ * invBLH;
  float Ez2 = SA2 * invBH + 2.f * SPQ * invBH + SQ2 * invBLH;
  float var = Ez2 - mean * mean;
  float g = br ? s_g1[i] : a_g1[i];
  float be = br ? s_be1[i] : a_be1[i];
  float sc = g / sqrtf(var + 1e-5f);
  ST[64 + br * 20 + i] = sc;
  ST[64 + br * 20 + 10 + i] = be - mean * sc;
}

// ---------------- fused layer2 via MFMA ----------------
template <int ACT>  // 0=relu, 1=tanh
__global__ __launch_bounds__(256) void fused_layer2_mfma(
    const float* __restrict__ PQ, int p_off, int q_off,
    const float* __restrict__ b1, const float* __restrict__ ST, int sc_off,
    const unsigned short* __restrict__ W2bf, const float* __restrict__ b2,
    const int* __restrict__ cl, float* __restrict__ Z2out,
    float* __restrict__ sumP, float* __restrict__ sumsqP) {
  __shared__ __align__(16) unsigned short Atile[64][264];  // pad 8 -> bank-uniform b128
  __shared__ float binS[10], binQ[10];
  int t = threadIdx.x;
  int rowBase = blockIdx.x * 64;
  if (t < 10) { binS[t] = 0.f; binQ[t] = 0.f; }
  // ---- stage h1 tile (bf16): thread t -> row t>>2, k-chunk (t&3)*64 ----
  {
    int m = t >> 2;
    int r = rowBase + m;
    int bb = r / 100, rem = r - bb * 100;
    int ii = rem / 10, jj = rem - ii * 10;
    const float* prow = PQ + (bb * 10 + ii) * 1024 + p_off;
    const float* qrow = PQ + (bb * 10 + jj) * 1024 + q_off;
    float sc = ST[sc_off + ii], sh = ST[sc_off + 10 + ii];
    int k0 = (t & 3) * 64;
    for (int k = k0; k < k0 + 64; k += 8) {
      float4 p0 = *(const float4*)&prow[k];
      float4 p1 = *(const float4*)&prow[k + 4];
      float4 q0 = *(const float4*)&qrow[k];
      float4 q1 = *(const float4*)&qrow[k + 4];
      float4 c0 = *(const float4*)&b1[k];
      float4 c1 = *(const float4*)&b1[k + 4];
      float z[8] = {p0.x + q0.x + c0.x, p0.y + q0.y + c0.y,
                    p0.z + q0.z + c0.z, p0.w + q0.w + c0.w,
                    p1.x + q1.x + c1.x, p1.y + q1.y + c1.y,
                    p1.z + q1.z + c1.z, p1.w + q1.w + c1.w};
      short8 hv;
#pragma unroll
      for (int e = 0; e < 8; ++e) {
        float zz = z[e] * sc + sh;
        float h;
        if (ACT) {
          float ex = __expf(2.f * zz);
          h = (ex - 1.f) / (ex + 1.f);
        } else {
          h = fmaxf(zz, 0.f);
        }
        hv[e] = (short)f2bf(h);
      }
      *(short8*)&Atile[m][k] = hv;
    }
  }
  __syncthreads();
  // ---- MFMA: wave w owns cols [w*64, w*64+64), rows all 64 ----
  int w = t >> 6, l = t & 63, li = l & 15, lg = l >> 4;
  int colBase = w * 64;
  f32x4 acc[4][4] = {};
  for (int ks = 0; ks < 8; ++ks) {
    int ka = ks * 32 + lg * 8;
    short8 afr[4], bfr[4];
#pragma unroll
    for (int fr = 0; fr < 4; ++fr)
      afr[fr] = *(const short8*)&Atile[fr * 16 + li][ka];
#pragma unroll
    for (int cf = 0; cf < 4; ++cf)
      bfr[cf] = *(const short8*)&W2bf[(colBase + cf * 16 + li) * 256 + ka];
#pragma unroll
    for (int fr = 0; fr < 4; ++fr)
#pragma unroll
      for (int cf = 0; cf < 4; ++cf)
        acc[fr][cf] = __builtin_amdgcn_mfma_f32_16x16x32_bf16(afr[fr], bfr[cf], acc[fr][cf], 0, 0, 0);
  }
  // ---- epilogue: bias, anchor-row write, BN2 sum/sumsq ----
  float b2v[4];
#pragma unroll
  for (int cf = 0; cf < 4; ++cf) b2v[cf] = b2[colBase + cf * 16 + li];
#pragma unroll
  for (int fr = 0; fr < 4; ++fr) {
#pragma unroll
    for (int reg = 0; reg < 4; ++reg) {
      int r = rowBase + fr * 16 + lg * 4 + reg;
      int bb = r / 100, rem = r - bb * 100;
      int ii = rem / 10, jj = rem - ii * 10;
      float z0 = acc[fr][0][reg] + b2v[0];
      float z1 = acc[fr][1][reg] + b2v[1];
      float z2 = acc[fr][2][reg] + b2v[2];
      float z3 = acc[fr][3][reg] + b2v[3];
      if (ii == cl[bb] - 1) {
        float* dst = Z2out + (bb * 10 + jj) * 256 + colBase + li;
        dst[0] = z0; dst[16] = z1; dst[32] = z2; dst[48] = z3;
      }
      float s = z0 + z1 + z2 + z3;
      float q = z0 * z0 + z1 * z1 + z2 * z2 + z3 * z3;
#pragma unroll
      for (int o = 1; o < 16; o <<= 1) {
        s += __shfl_xor(s, o);
        q += __shfl_xor(q, o);
      }
      if (li == 0) {
        atomicAdd(&binS[ii], s);
        atomicAdd(&binQ[ii], q);
      }
    }
  }
  __syncthreads();
  if (t < 10) {
    atomicAdd(&sumP[t], binS[t]);
    atomicAdd(&sumsqP[t], binQ[t]);
  }
}

// ---------------- BN2 finalize ----------------
__global__ void finalize_bn2(const float* __restrict__ a_g2, const float* __restrict__ a_be2,
                             const float* __restrict__ s_g2, const float* __restrict__ s_be2,
                             float* __restrict__ ST) {
  int t = threadIdx.x;
  if (t >= 20) return;
  int br = t / 10, i = t % 10;
  const float invN = 1.f / (512.f * 10.f * 256.f);
  float m = ST[104 + br * 20 + i] * invN;
  float v = ST[104 + br * 20 + 10 + i] * invN - m * m;
  float g = br ? s_g2[i] : a_g2[i];
  float be = br ? s_be2[i] : a_be2[i];
  float sc = g / sqrtf(v + 1e-5f);
  ST[144 + br * 20 + i] = sc;
  ST[144 + br * 20 + 10 + i] = be - m * sc;
}

// ---------------- generic fp32 tiled GEMM (GRU) ----------------
__global__ __launch_bounds__(256) void gemm64(const float* __restrict__ A,
                                              const float* __restrict__ Wt,
                                              float* __restrict__ C,
                                              const float* __restrict__ bias,
                                              int M, int N, int K) {
  __shared__ float As[16][68];
  __shared__ float Bs[16][68];
  int t = threadIdx.x;
  int bm = blockIdx.x * 64, bn = blockIdx.y * 64;
  int tx = t & 15, ty = t >> 4;
  float acc[4][4] = {};
  for (int kc = 0; kc < K; kc += 16) {
#pragma unroll
    for (int s = 0; s < 4; ++s) {
      int idx = t + s * 256;
      int k = idx & 15, m = idx >> 4;
      As[k][m] = A[(bm + m) * K + kc + k];
    }
#pragma unroll
    for (int s = 0; s < 4; ++s) {
      int idx = t + s * 256;
      int n = idx & 63, k = idx >> 6;
      Bs[k][n] = Wt[(kc + k) * N + bn + n];
    }
    __syncthreads();
#pragma unroll
    for (int k = 0; k < 16; ++k) {
      float4 a4 = *(const float4*)&As[k][ty * 4];
      float4 b4 = *(const float4*)&Bs[k][tx * 4];
      float av[4] = {a4.x, a4.y, a4.z, a4.w};
      float bv[4] = {b4.x, b4.y, b4.z, b4.w};
#pragma unroll
      for (int mi = 0; mi < 4; ++mi)
#pragma unroll
        for (int ni = 0; ni < 4; ++ni) acc[mi][ni] += av[mi] * bv[ni];
    }
    __syncthreads();
  }
#pragma unroll
  for (int mi = 0; mi < 4; ++mi) {
    int row = bm + ty * 4 + mi;
    int col = bn + tx * 4;
    float4 o;
    o.x = acc[mi][0]; o.y = acc[mi][1]; o.z = acc[mi][2]; o.w = acc[mi][3];
    if (bias) { o.x += bias[col]; o.y += bias[col + 1]; o.z += bias[col + 2]; o.w += bias[col + 3]; }
    *(float4*)&C[row * N + col] = o;
  }
}

// ---------------- postproc ----------------
__global__ __launch_bounds__(256) void postproc_kernel(
    const float* __restrict__ Z2a, const float* __restrict__ Z2s, const float* __restrict__ ST,
    const float* __restrict__ a_w3, const float* __restrict__ a_b3,
    const float* __restrict__ mu_w, const float* __restrict__ mu_b,
    const float* __restrict__ sg_w, const float* __restrict__ sg_b,
    const float* __restrict__ aij_eps, const float* __restrict__ sij_eps,
    const int* __restrict__ cl, const float* __restrict__ utt,
    float* __restrict__ message, float* __restrict__ h0out) {
  int b = blockIdx.x, t = threadIdx.x;
  int a = cl[b] - 1;
  float sc2a = ST[144 + a], sh2a = ST[154 + a];
  float sc2s = ST[164 + a], sh2s = ST[174 + a];
  float w3 = a_w3[t], mw = mu_w[t], sw = sg_w[t];
  __shared__ float red[30];
  if (t < 30) red[t] = 0.f;
  __syncthreads();
#pragma unroll
  for (int j = 0; j < 10; ++j) {
    float za = Z2a[(b * 10 + j) * 256 + t];
    float va = fmaxf(za * sc2a + sh2a, 0.f);
    float zs = Z2s[(b * 10 + j) * 256 + t];
    float vs = tanhf(zs * sc2s + sh2s);
    float pa = wred64(va * w3);
    float pm = wred64(vs * mw);
    float ps = wred64(vs * sw);
    if ((t & 63) == 0) {
      atomicAdd(&red[j], pa);
      atomicAdd(&red[10 + j], pm);
      atomicAdd(&red[20 + j], ps);
    }
  }
  __syncthreads();
  __shared__ float pw[10];
  __shared__ float wijs[16];
  if (t < 10) {
    int j = t;
    float amij = red[j] + a_b3[0];
    float amu = softplusf(amij) + 0.01f;
    float astd = sqrtf(softplusf((1.f - amu) * amu) + 0.01f);
    float ae = aij_eps[b * 100 + a * 10 + j];
    float aij = softplusf(ae * astd + amu) + 0.01f;
    float smu = red[10 + j] + mu_b[0];
    float ssg = red[20 + j] + sg_b[0];
    float se = sij_eps[b * 100 + a * 10 + j];
    float sij = se * sqrtf(aij * ssg * ssg) + aij * smu;
    wijs[j] = aij * sij;
  }
  __syncthreads();
  if (t == 0) {
    float mx = -1e30f;
    for (int j = 0; j < a; ++j) mx = fmaxf(mx, wijs[j]);
    float e[10];
    float den = 0.f;
    for (int j = 0; j < a; ++j) { e[j] = expf(wijs[j] - mx); den += e[j]; }
    for (int j = 0; j < 10; ++j) pw[j] = (j < a) ? e[j] / den : 0.f;
  }
  __syncthreads();
#pragma unroll
  for (int dd = 0; dd < 2; ++dd) {
    int d = t + dd * 256;
    float mv = 0.f;
#pragma unroll
    for (int j = 0; j < 10; ++j) mv += pw[j] * utt[(b * 10 + j) * 512 + d];
    message[b * 512 + d] = mv;
  }
  float u1 = utt[(b * 10 + a) * 512 + t];
  float u2 = utt[(b * 10 + a) * 512 + 256 + t];
  h0out[b * 256 + t] = u1 + u2;
}

// ---------------- GRU elementwise ----------------
__global__ __launch_bounds__(256) void gru_final(const float* __restrict__ gi,
                                                 const float* __restrict__ gh,
                                                 const float* __restrict__ h0,
                                                 float* __restrict__ out) {
  int idx = blockIdx.x * 256 + threadIdx.x;
  int b = idx >> 8, h = idx & 255;
  float ir = gi[b * 768 + h], iz = gi[b * 768 + 256 + h], inn = gi[b * 768 + 512 + h];
  float hr = gh[b * 768 + h], hz = gh[b * 768 + 256 + h], hn = gh[b * 768 + 512 + h];
  float r = 1.f / (1.f + expf(-(ir + hr)));
  float z = 1.f / (1.f + expf(-(iz + hz)));
  float n = tanhf(inn + r * hn);
  out[idx] = (1.f - z) * n + z * h0[b * 256 + h];
}

extern "C" void kernel_launch(void* const* d_in, const int* in_sizes, int n_in,
                              void* d_out, int out_size, void* d_ws, size_t ws_size,
                              hipStream_t stream) {
  const float* utt = (const float*)d_in[0];
  const float* aij_eps = (const float*)d_in[1];
  const float* sij_eps = (const float*)d_in[2];
  const int* cl = (const int*)d_in[3];
  const float* a_w1 = (const float*)d_in[4];
  const float* a_b1 = (const float*)d_in[5];
  const float* a_g1 = (const float*)d_in[6];
  const float* a_be1 = (const float*)d_in[7];
  const float* a_w2 = (const float*)d_in[8];
  const float* a_b2 = (const float*)d_in[9];
  const float* a_g2 = (const float*)d_in[10];
  const float* a_be2 = (const float*)d_in[11];
  const float* a_w3 = (const float*)d_in[12];
  const float* a_b3 = (const float*)d_in[13];
  const float* s_w1 = (const float*)d_in[14];
  const float* s_b1 = (const float*)d_in[15];
  const float* s_g1 = (const float*)d_in[16];
  const float* s_be1 = (const float*)d_in[17];
  const float* s_w2 = (const float*)d_in[18];
  const float* s_b2 = (const float*)d_in[19];
  const float* s_g2 = (const float*)d_in[20];
  const float* s_be2 = (const float*)d_in[21];
  const float* mu_w = (const float*)d_in[22];
  const float* mu_b = (const float*)d_in[23];
  const float* sg_w = (const float*)d_in[24];
  const float* sg_b = (const float*)d_in[25];
  const float* gru_wi = (const float*)d_in[26];
  const float* gru_wh = (const float*)d_in[27];
  const float* gru_bi = (const float*)d_in[28];
  const float* gru_bh = (const float*)d_in[29];

  float* ws = (float*)d_ws;
  float* ST = ws;                        // 256
  float* wiT = ws + 256;                 // 393216
  float* whT = wiT + 393216;             // 196608
  unsigned short* uttbf = (unsigned short*)(whT + 196608);   // 2621440 shorts
  unsigned short* Wcatbf = uttbf + 2621440;                  // 524288 shorts
  unsigned short* W2abf = Wcatbf + 524288;                   // 65536 shorts
  unsigned short* W2sbf = W2abf + 65536;                     // 65536 shorts
  float* PQ = (float*)(W2sbf + 65536);   // 5242880
  float* Qba = PQ + 5242880;             // 131072
  float* Qbs = Qba + 131072;             // 131072
  float* Z2a = Qbs + 131072;             // 1310720
  float* Z2s = Z2a + 1310720;            // 1310720
  // msg/h0/gi/gh alias PQ (dead after fused_layer2)
  float* msg = PQ;                       // 262144
  float* h0 = PQ + 262144;               // 131072
  float* gi = PQ + 393216;               // 393216
  float* gh = PQ + 786432;               // 393216

  hipMemsetAsync(ST, 0, 256 * sizeof(float), stream);
  prep_weights<<<1024, 256, 0, stream>>>(utt, a_w1, s_w1, a_w2, s_w2, gru_wi, gru_wh,
                                         wiT, whT, uttbf, Wcatbf, W2abf, W2sbf);
  gemm_pq_mfma<<<dim3(80, 4), 256, 0, stream>>>(uttbf, Wcatbf, PQ);
  qstats_kernel<<<512, 256, 0, stream>>>(PQ, Qba, Qbs, ST);
  pstats_kernel<<<dim3(10, 8), 256, 0, stream>>>(PQ, Qba, Qbs, a_b1, s_b1, ST);
  finalize_bn1<<<1, 64, 0, stream>>>(a_b1, s_b1, a_g1, a_be1, s_g1, s_be1, ST);
  fused_layer2_mfma<0><<<800, 256, 0, stream>>>(PQ, 0, 256, a_b1, ST, 64, W2abf, a_b2,
                                                cl, Z2a, ST + 104, ST + 114);
  fused_layer2_mfma<1><<<800, 256, 0, stream>>>(PQ, 512, 768, s_b1, ST, 84, W2sbf, s_b2,
                                                cl, Z2s, ST + 124, ST + 134);
  finalize_bn2<<<1, 32, 0, stream>>>(a_g2, a_be2, s_g2, s_be2, ST);
  postproc_kernel<<<512, 256, 0, stream>>>(Z2a, Z2s, ST, a_w3, a_b3, mu_w, mu_b, sg_w, sg_b,
                                           aij_eps, sij_eps, cl, utt, msg, h0);
  gemm64<<<dim3(8, 12), 256, 0, stream>>>(msg, wiT, gi, gru_bi, 512, 768, 512);
  gemm64<<<dim3(8, 12), 256, 0, stream>>>(h0, whT, gh, gru_bh, 512, 768, 256);
  gru_final<<<512, 256, 0, stream>>>(gi, gh, h0, (float*)d_out);
}

// Round 3
// 274.325 us; speedup vs baseline: 2.3587x; 1.3819x over previous
//
#include <hip/hip_runtime.h>
#include <math.h>

// ContextEncoder: B=512, L=10, H=256, D=512.
//  prep: bf16 conversions (utt, Wcat, W2a, W2s, gru wi/wh — no transposes needed).
//  gemm_mfma: generic bf16 MFMA GEMM, C[M][N] = A[M][K] @ Bw[N][K]^T (+bias).
//  stats_kernel: one pass over PQ -> per-block BN1 moment partials (no atomics).
//  reduce_bn1: sum partials + closed-form BN1 scale/shift.
//  fused_layer2_mfma: h1 tile (bf16, LDS) -> MFMA z2 -> BN2 stats + anchor rows.
//  finalize_bn2, postproc (emits bf16 msg/h0), GRU via gemm_mfma + elementwise.

typedef __attribute__((ext_vector_type(8))) short short8;
typedef __attribute__((ext_vector_type(4))) float f32x4;

__device__ __forceinline__ float softplusf(float x) {
  return x > 0.f ? x + log1pf(expf(-x)) : log1pf(expf(x));
}
__device__ __forceinline__ float wred64(float v) {
#pragma unroll
  for (int o = 32; o > 0; o >>= 1) v += __shfl_down(v, o);
  return v;
}
__device__ __forceinline__ unsigned short f2bf(float f) {
  unsigned int u = __float_as_uint(f);
  u += 0x7fffu + ((u >> 16) & 1u);
  return (unsigned short)(u >> 16);
}

// ---------------- prep: bf16 conversions ----------------
__global__ __launch_bounds__(256) void prep_weights(
    const float* __restrict__ utt,
    const float* __restrict__ a_w1, const float* __restrict__ s_w1,
    const float* __restrict__ a_w2, const float* __restrict__ s_w2,
    const float* __restrict__ gru_wi, const float* __restrict__ gru_wh,
    unsigned short* __restrict__ uttbf, unsigned short* __restrict__ Wcatbf,
    unsigned short* __restrict__ W2abf, unsigned short* __restrict__ W2sbf,
    unsigned short* __restrict__ wibf, unsigned short* __restrict__ whbf) {
  const int total = 2621440 + 524288 + 65536 + 65536 + 393216 + 196608;
  for (int idx = blockIdx.x * 256 + threadIdx.x; idx < total; idx += gridDim.x * 256) {
    int id = idx;
    if (id < 2621440) { uttbf[id] = f2bf(utt[id]); continue; }
    id -= 2621440;
    if (id < 524288) {  // Wcatbf[c][k], c<1024, k<512
      int c = id >> 9, k = id & 511;
      float v;
      if (c < 256)       v = a_w1[c * 1024 + k];
      else if (c < 512)  v = a_w1[(c - 256) * 1024 + 512 + k];
      else if (c < 768)  v = s_w1[(c - 512) * 1024 + k];
      else               v = s_w1[(c - 768) * 1024 + 512 + k];
      Wcatbf[id] = f2bf(v); continue;
    }
    id -= 524288;
    if (id < 65536) { W2abf[id] = f2bf(a_w2[id]); continue; }
    id -= 65536;
    if (id < 65536) { W2sbf[id] = f2bf(s_w2[id]); continue; }
    id -= 65536;
    if (id < 393216) { wibf[id] = f2bf(gru_wi[id]); continue; }
    id -= 393216;
    whbf[id] = f2bf(gru_wh[id]);
  }
}

// ---------------- generic MFMA GEMM: C[M][N] = A[M][K] @ Bw[N][K]^T (+bias) ----------------
// grid: (M/64, N/256); 4 waves, wave w owns 64 cols.
__global__ __launch_bounds__(256) void gemm_mfma(
    const unsigned short* __restrict__ A, const unsigned short* __restrict__ Bw,
    float* __restrict__ C, const float* __restrict__ bias, int K, int N) {
  int t = threadIdx.x;
  int w = t >> 6, l = t & 63, li = l & 15, lg = l >> 4;
  int rowBase = blockIdx.x * 64;
  int colBase = blockIdx.y * 256 + w * 64;
  f32x4 acc[4][4] = {};
  const unsigned short* Arow[4];
  const unsigned short* Brow[4];
#pragma unroll
  for (int fr = 0; fr < 4; ++fr) Arow[fr] = A + (rowBase + fr * 16 + li) * K;
#pragma unroll
  for (int cf = 0; cf < 4; ++cf) Brow[cf] = Bw + (colBase + cf * 16 + li) * K;
  for (int ks = 0; ks < K / 32; ++ks) {
    int ka = ks * 32 + lg * 8;
    short8 afr[4], bfr[4];
#pragma unroll
    for (int fr = 0; fr < 4; ++fr) afr[fr] = *(const short8*)&Arow[fr][ka];
#pragma unroll
    for (int cf = 0; cf < 4; ++cf) bfr[cf] = *(const short8*)&Brow[cf][ka];
#pragma unroll
    for (int fr = 0; fr < 4; ++fr)
#pragma unroll
      for (int cf = 0; cf < 4; ++cf)
        acc[fr][cf] = __builtin_amdgcn_mfma_f32_16x16x32_bf16(afr[fr], bfr[cf], acc[fr][cf], 0, 0, 0);
  }
  float b2v[4] = {0.f, 0.f, 0.f, 0.f};
  if (bias) {
#pragma unroll
    for (int cf = 0; cf < 4; ++cf) b2v[cf] = bias[colBase + cf * 16 + li];
  }
#pragma unroll
  for (int fr = 0; fr < 4; ++fr)
#pragma unroll
    for (int reg = 0; reg < 4; ++reg) {
      int r = rowBase + fr * 16 + lg * 4 + reg;
      float* crow = C + r * N + colBase + li;
#pragma unroll
      for (int cf = 0; cf < 4; ++cf) crow[cf * 16] = acc[fr][cf][reg] + b2v[cf];
    }
}

// ---------------- BN1 stats: one block per dialog, per-block partials ----------------
__global__ __launch_bounds__(256) void stats_kernel(
    const float* __restrict__ PQ, const float* __restrict__ a_b1,
    const float* __restrict__ s_b1, float* __restrict__ Part) {
  __shared__ float lbins[4][64];
  int b = blockIdx.x, t = threadIdx.x;
  int w = t >> 6, l = t & 63;
  const float* base = PQ + b * 10240;
  // ---- branch a (bins 0,1 and 4..33) ----
  {
    float P[10], Q[10];
#pragma unroll
    for (int j = 0; j < 10; ++j) {
      P[j] = base[j * 1024 + t];
      Q[j] = base[j * 1024 + 256 + t];
    }
    float sq = 0.f, sq2 = 0.f;
#pragma unroll
    for (int j = 0; j < 10; ++j) { sq += Q[j]; sq2 += Q[j] * Q[j]; }
    float qbar = sq * 0.1f;
    float bb1 = a_b1[t];
    float r;
    r = wred64(sq);  if (l == 0) lbins[w][0] = r;
    r = wred64(sq2); if (l == 0) lbins[w][1] = r;
#pragma unroll
    for (int i = 0; i < 10; ++i) {
      float a = P[i] + bb1;
      r = wred64(P[i]);     if (l == 0) lbins[w][4 + i * 3] = r;
      r = wred64(a * a);    if (l == 0) lbins[w][5 + i * 3] = r;
      r = wred64(a * qbar); if (l == 0) lbins[w][6 + i * 3] = r;
    }
  }
  // ---- branch s (bins 2,3 and 34..63) ----
  {
    float P[10], Q[10];
#pragma unroll
    for (int j = 0; j < 10; ++j) {
      P[j] = base[j * 1024 + 512 + t];
      Q[j] = base[j * 1024 + 768 + t];
    }
    float sq = 0.f, sq2 = 0.f;
#pragma unroll
    for (int j = 0; j < 10; ++j) { sq += Q[j]; sq2 += Q[j] * Q[j]; }
    float qbar = sq * 0.1f;
    float bb1 = s_b1[t];
    float r;
    r = wred64(sq);  if (l == 0) lbins[w][2] = r;
    r = wred64(sq2); if (l == 0) lbins[w][3] = r;
#pragma unroll
    for (int i = 0; i < 10; ++i) {
      float a = P[i] + bb1;
      r = wred64(P[i]);     if (l == 0) lbins[w][34 + i * 3] = r;
      r = wred64(a * a);    if (l == 0) lbins[w][35 + i * 3] = r;
      r = wred64(a * qbar); if (l == 0) lbins[w][36 + i * 3] = r;
    }
  }
  __syncthreads();
  if (t < 64) Part[b * 64 + t] = lbins[0][t] + lbins[1][t] + lbins[2][t] + lbins[3][t];
}

// ---------------- reduce partials + BN1 closed-form finalize ----------------
__global__ void reduce_bn1(const float* __restrict__ Part,
                           const float* __restrict__ a_b1, const float* __restrict__ s_b1,
                           const float* __restrict__ a_g1, const float* __restrict__ a_be1,
                           const float* __restrict__ s_g1, const float* __restrict__ s_be1,
                           float* __restrict__ ST) {
  __shared__ float tmp[256];
  __shared__ float mom[64];
  int t = threadIdx.x;
  int v = t & 63, c = t >> 6;
  float s = 0.f;
  for (int b = c * 128; b < (c + 1) * 128; ++b) s += Part[b * 64 + v];
  tmp[t] = s;
  __syncthreads();
  if (t < 64) mom[t] = tmp[t] + tmp[t + 64] + tmp[t + 128] + tmp[t + 192];
  __syncthreads();
  if (t < 20) {
    int br = t / 10, i = t % 10;
    const float* b1 = br ? s_b1 : a_b1;
    float bsum = 0.f;
    for (int h = 0; h < 256; ++h) bsum += b1[h];
    float meanb1 = bsum * (1.f / 256.f);
    const float invBH = 1.f / (512.f * 256.f);
    const float invBLH = 1.f / (512.f * 10.f * 256.f);
    int basei = (br ? 34 : 4) + i * 3;
    float SP = mom[basei + 0], SA2 = mom[basei + 1], SPQ = mom[basei + 2];
    float SQ = mom[br ? 2 : 0], SQ2 = mom[br ? 3 : 1];
    float mean = SP * invBH + meanb1 + SQ * invBLH;
    float Ez2 = SA2 * invBH + 2.f * SPQ * invBH + SQ2 * invBLH;
    float var = Ez2 - mean * mean;
    float g = br ? s_g1[i] : a_g1[i];
    float be = br ? s_be1[i] : a_be1[i];
    float sc = g / sqrtf(var + 1e-5f);
    ST[64 + br * 20 + i] = sc;
    ST[64 + br * 20 + 10 + i] = be - mean * sc;
  }
}

// ---------------- fused layer2 via MFMA ----------------
template <int ACT>  // 0=relu, 1=tanh
__global__ __launch_bounds__(256) void fused_layer2_mfma(
    const float* __restrict__ PQ, int p_off, int q_off,
    const float* __restrict__ b1, const float* __restrict__ ST, int sc_off,
    const unsigned short* __restrict__ W2bf, const float* __restrict__ b2,
    const int* __restrict__ cl, float* __restrict__ Z2out,
    float* __restrict__ sumP, float* __restrict__ sumsqP) {
  __shared__ __align__(16) unsigned short Atile[64][264];
  __shared__ float binS[10], binQ[10];
  int t = threadIdx.x;
  int rowBase = blockIdx.x * 64;
  if (t < 10) { binS[t] = 0.f; binQ[t] = 0.f; }
  {
    int m = t >> 2;
    int r = rowBase + m;
    int bb = r / 100, rem = r - bb * 100;
    int ii = rem / 10, jj = rem - ii * 10;
    const float* prow = PQ + (bb * 10 + ii) * 1024 + p_off;
    const float* qrow = PQ + (bb * 10 + jj) * 1024 + q_off;
    float sc = ST[sc_off + ii], sh = ST[sc_off + 10 + ii];
    int k0 = (t & 3) * 64;
    for (int k = k0; k < k0 + 64; k += 8) {
      float4 p0 = *(const float4*)&prow[k];
      float4 p1 = *(const float4*)&prow[k + 4];
      float4 q0 = *(const float4*)&qrow[k];
      float4 q1 = *(const float4*)&qrow[k + 4];
      float4 c0 = *(const float4*)&b1[k];
      float4 c1 = *(const float4*)&b1[k + 4];
      float z[8] = {p0.x + q0.x + c0.x, p0.y + q0.y + c0.y,
                    p0.z + q0.z + c0.z, p0.w + q0.w + c0.w,
                    p1.x + q1.x + c1.x, p1.y + q1.y + c1.y,
                    p1.z + q1.z + c1.z, p1.w + q1.w + c1.w};
      short8 hv;
#pragma unroll
      for (int e = 0; e < 8; ++e) {
        float zz = z[e] * sc + sh;
        float h;
        if (ACT) {
          float ex = __expf(2.f * zz);
          h = (ex - 1.f) / (ex + 1.f);
        } else {
          h = fmaxf(zz, 0.f);
        }
        hv[e] = (short)f2bf(h);
      }
      *(short8*)&Atile[m][k] = hv;
    }
  }
  __syncthreads();
  int w = t >> 6, l = t & 63, li = l & 15, lg = l >> 4;
  int colBase = w * 64;
  f32x4 acc[4][4] = {};
  for (int ks = 0; ks < 8; ++ks) {
    int ka = ks * 32 + lg * 8;
    short8 afr[4], bfr[4];
#pragma unroll
    for (int fr = 0; fr < 4; ++fr)
      afr[fr] = *(const short8*)&Atile[fr * 16 + li][ka];
#pragma unroll
    for (int cf = 0; cf < 4; ++cf)
      bfr[cf] = *(const short8*)&W2bf[(colBase + cf * 16 + li) * 256 + ka];
#pragma unroll
    for (int fr = 0; fr < 4; ++fr)
#pragma unroll
      for (int cf = 0; cf < 4; ++cf)
        acc[fr][cf] = __builtin_amdgcn_mfma_f32_16x16x32_bf16(afr[fr], bfr[cf], acc[fr][cf], 0, 0, 0);
  }
  float b2v[4];
#pragma unroll
  for (int cf = 0; cf < 4; ++cf) b2v[cf] = b2[colBase + cf * 16 + li];
#pragma unroll
  for (int fr = 0; fr < 4; ++fr) {
#pragma unroll
    for (int reg = 0; reg < 4; ++reg) {
      int r = rowBase + fr * 16 + lg * 4 + reg;
      int bb = r / 100, rem = r - bb * 100;
      int ii = rem / 10, jj = rem - ii * 10;
      float z0 = acc[fr][0][reg] + b2v[0];
      float z1 = acc[fr][1][reg] + b2v[1];
      float z2 = acc[fr][2][reg] + b2v[2];
      float z3 = acc[fr][3][reg] + b2v[3];
      if (ii == cl[bb] - 1) {
        float* dst = Z2out + (bb * 10 + jj) * 256 + colBase + li;
        dst[0] = z0; dst[16] = z1; dst[32] = z2; dst[48] = z3;
      }
      float s = z0 + z1 + z2 + z3;
      float q = z0 * z0 + z1 * z1 + z2 * z2 + z3 * z3;
#pragma unroll
      for (int o = 1; o < 16; o <<= 1) {
        s += __shfl_xor(s, o);
        q += __shfl_xor(q, o);
      }
      if (li == 0) {
        atomicAdd(&binS[ii], s);
        atomicAdd(&binQ[ii], q);
      }
    }
  }
  __syncthreads();
  if (t < 10) {
    atomicAdd(&sumP[t], binS[t]);
    atomicAdd(&sumsqP[t], binQ[t]);
  }
}

// ---------------- BN2 finalize ----------------
__global__ void finalize_bn2(const float* __restrict__ a_g2, const float* __restrict__ a_be2,
                             const float* __restrict__ s_g2, const float* __restrict__ s_be2,
                             float* __restrict__ ST) {
  int t = threadIdx.x;
  if (t >= 20) return;
  int br = t / 10, i = t % 10;
  const float invN = 1.f / (512.f * 10.f * 256.f);
  float m = ST[104 + br * 20 + i] * invN;
  float v = ST[104 + br * 20 + 10 + i] * invN - m * m;
  float g = br ? s_g2[i] : a_g2[i];
  float be = br ? s_be2[i] : a_be2[i];
  float sc = g / sqrtf(v + 1e-5f);
  ST[144 + br * 20 + i] = sc;
  ST[144 + br * 20 + 10 + i] = be - m * sc;
}

// ---------------- postproc ----------------
__global__ __launch_bounds__(256) void postproc_kernel(
    const float* __restrict__ Z2a, const float* __restrict__ Z2s, const float* __restrict__ ST,
    const float* __restrict__ a_w3, const float* __restrict__ a_b3,
    const float* __restrict__ mu_w, const float* __restrict__ mu_b,
    const float* __restrict__ sg_w, const float* __restrict__ sg_b,
    const float* __restrict__ aij_eps, const float* __restrict__ sij_eps,
    const int* __restrict__ cl, const float* __restrict__ utt,
    unsigned short* __restrict__ msgbf, unsigned short* __restrict__ h0bf,
    float* __restrict__ h0out) {
  int b = blockIdx.x, t = threadIdx.x;
  int a = cl[b] - 1;
  float sc2a = ST[144 + a], sh2a = ST[154 + a];
  float sc2s = ST[164 + a], sh2s = ST[174 + a];
  float w3 = a_w3[t], mw = mu_w[t], sw = sg_w[t];
  __shared__ float red[30];
  if (t < 30) red[t] = 0.f;
  __syncthreads();
#pragma unroll
  for (int j = 0; j < 10; ++j) {
    float za = Z2a[(b * 10 + j) * 256 + t];
    float va = fmaxf(za * sc2a + sh2a, 0.f);
    float zs = Z2s[(b * 10 + j) * 256 + t];
    float vs = tanhf(zs * sc2s + sh2s);
    float pa = wred64(va * w3);
    float pm = wred64(vs * mw);
    float ps = wred64(vs * sw);
    if ((t & 63) == 0) {
      atomicAdd(&red[j], pa);
      atomicAdd(&red[10 + j], pm);
      atomicAdd(&red[20 + j], ps);
    }
  }
  __syncthreads();
  __shared__ float pw[10];
  __shared__ float wijs[16];
  if (t < 10) {
    int j = t;
    float amij = red[j] + a_b3[0];
    float amu = softplusf(amij) + 0.01f;
    float astd = sqrtf(softplusf((1.f - amu) * amu) + 0.01f);
    float ae = aij_eps[b * 100 + a * 10 + j];
    float aij = softplusf(ae * astd + amu) + 0.01f;
    float smu = red[10 + j] + mu_b[0];
    float ssg = red[20 + j] + sg_b[0];
    float se = sij_eps[b * 100 + a * 10 + j];
    float sij = se * sqrtf(aij * ssg * ssg) + aij * smu;
    wijs[j] = aij * sij;
  }
  __syncthreads();
  if (t == 0) {
    float mx = -1e30f;
    for (int j = 0; j < a; ++j) mx = fmaxf(mx, wijs[j]);
    float e[10];
    float den = 0.f;
    for (int j = 0; j < a; ++j) { e[j] = expf(wijs[j] - mx); den += e[j]; }
    for (int j = 0; j < 10; ++j) pw[j] = (j < a) ? e[j] / den : 0.f;
  }
  __syncthreads();
#pragma unroll
  for (int dd = 0; dd < 2; ++dd) {
    int d = t + dd * 256;
    float mv = 0.f;
#pragma unroll
    for (int j = 0; j < 10; ++j) mv += pw[j] * utt[(b * 10 + j) * 512 + d];
    msgbf[b * 512 + d] = f2bf(mv);
  }
  float u1 = utt[(b * 10 + a) * 512 + t];
  float u2 = utt[(b * 10 + a) * 512 + 256 + t];
  float h0v = u1 + u2;
  h0out[b * 256 + t] = h0v;
  h0bf[b * 256 + t] = f2bf(h0v);
}

// ---------------- GRU elementwise ----------------
__global__ __launch_bounds__(256) void gru_final(const float* __restrict__ gi,
                                                 const float* __restrict__ gh,
                                                 const float* __restrict__ h0,
                                                 float* __restrict__ out) {
  int idx = blockIdx.x * 256 + threadIdx.x;
  int b = idx >> 8, h = idx & 255;
  float ir = gi[b * 768 + h], iz = gi[b * 768 + 256 + h], inn = gi[b * 768 + 512 + h];
  float hr = gh[b * 768 + h], hz = gh[b * 768 + 256 + h], hn = gh[b * 768 + 512 + h];
  float r = 1.f / (1.f + expf(-(ir + hr)));
  float z = 1.f / (1.f + expf(-(iz + hz)));
  float n = tanhf(inn + r * hn);
  out[idx] = (1.f - z) * n + z * h0[b * 256 + h];
}

extern "C" void kernel_launch(void* const* d_in, const int* in_sizes, int n_in,
                              void* d_out, int out_size, void* d_ws, size_t ws_size,
                              hipStream_t stream) {
  const float* utt = (const float*)d_in[0];
  const float* aij_eps = (const float*)d_in[1];
  const float* sij_eps = (const float*)d_in[2];
  const int* cl = (const int*)d_in[3];
  const float* a_w1 = (const float*)d_in[4];
  const float* a_b1 = (const float*)d_in[5];
  const float* a_g1 = (const float*)d_in[6];
  const float* a_be1 = (const float*)d_in[7];
  const float* a_w2 = (const float*)d_in[8];
  const float* a_b2 = (const float*)d_in[9];
  const float* a_g2 = (const float*)d_in[10];
  const float* a_be2 = (const float*)d_in[11];
  const float* a_w3 = (const float*)d_in[12];
  const float* a_b3 = (const float*)d_in[13];
  const float* s_w1 = (const float*)d_in[14];
  const float* s_b1 = (const float*)d_in[15];
  const float* s_g1 = (const float*)d_in[16];
  const float* s_be1 = (const float*)d_in[17];
  const float* s_w2 = (const float*)d_in[18];
  const float* s_b2 = (const float*)d_in[19];
  const float* s_g2 = (const float*)d_in[20];
  const float* s_be2 = (const float*)d_in[21];
  const float* mu_w = (const float*)d_in[22];
  const float* mu_b = (const float*)d_in[23];
  const float* sg_w = (const float*)d_in[24];
  const float* sg_b = (const float*)d_in[25];
  const float* gru_wi = (const float*)d_in[26];
  const float* gru_wh = (const float*)d_in[27];
  const float* gru_bi = (const float*)d_in[28];
  const float* gru_bh = (const float*)d_in[29];

  float* ws = (float*)d_ws;
  float* ST = ws;                                            // 256 floats
  unsigned short* uttbf = (unsigned short*)(ws + 256);       // 2621440 sh
  unsigned short* Wcatbf = uttbf + 2621440;                  // 524288 sh
  unsigned short* W2abf = Wcatbf + 524288;                   // 65536 sh
  unsigned short* W2sbf = W2abf + 65536;                     // 65536 sh
  unsigned short* wibf = W2sbf + 65536;                      // 393216 sh
  unsigned short* whbf = wibf + 393216;                      // 196608 sh
  float* PQ = (float*)(whbf + 196608);                       // 5242880 f
  float* Z2a = PQ + 5242880;                                 // 1310720 f
  float* Z2s = Z2a + 1310720;                                // 1310720 f
  float* Part = Z2s + 1310720;                               // 32768 f
  // postproc/GRU buffers alias PQ (dead after fused_layer2)
  unsigned short* msgbf = (unsigned short*)PQ;               // 262144 sh
  unsigned short* h0bf = msgbf + 262144;                     // 131072 sh
  float* h0 = PQ + 196608;                                   // 131072 f
  float* gi = PQ + 327680;                                   // 393216 f
  float* gh = gi + 393216;                                   // 393216 f

  hipMemsetAsync(ST, 0, 256 * sizeof(float), stream);
  prep_weights<<<1024, 256, 0, stream>>>(utt, a_w1, s_w1, a_w2, s_w2, gru_wi, gru_wh,
                                         uttbf, Wcatbf, W2abf, W2sbf, wibf, whbf);
  gemm_mfma<<<dim3(80, 4), 256, 0, stream>>>(uttbf, Wcatbf, PQ, nullptr, 512, 1024);
  stats_kernel<<<512, 256, 0, stream>>>(PQ, a_b1, s_b1, Part);
  reduce_bn1<<<1, 256, 0, stream>>>(Part, a_b1, s_b1, a_g1, a_be1, s_g1, s_be1, ST);
  fused_layer2_mfma<0><<<800, 256, 0, stream>>>(PQ, 0, 256, a_b1, ST, 64, W2abf, a_b2,
                                                cl, Z2a, ST + 104, ST + 114);
  fused_layer2_mfma<1><<<800, 256, 0, stream>>>(PQ, 512, 768, s_b1, ST, 84, W2sbf, s_b2,
                                                cl, Z2s, ST + 124, ST + 134);
  finalize_bn2<<<1, 32, 0, stream>>>(a_g2, a_be2, s_g2, s_be2, ST);
  postproc_kernel<<<512, 256, 0, stream>>>(Z2a, Z2s, ST, a_w3, a_b3, mu_w, mu_b, sg_w, sg_b,
                                           aij_eps, sij_eps, cl, utt, msgbf, h0bf, h0);
  gemm_mfma<<<dim3(8, 3), 256, 0, stream>>>(msgbf, wibf, gi, gru_bi, 512, 768);
  gemm_mfma<<<dim3(8, 3), 256, 0, stream>>>(h0bf, whbf, gh, gru_bh, 256, 768);
  gru_final<<<512, 256, 0, stream>>>(gi, gh, h0, (float*)d_out);
}

// Round 5
// 203.799 us; speedup vs baseline: 3.1750x; 1.3461x over previous
//
#include <hip/hip_runtime.h>
#include <math.h>

// ContextEncoder: B=512, L=10, H=256, D=512.
//  prep: bf16 conversions (utt, Wcat, W2a, W2s, gru wi/wh).
//  gemm_mfma: generic bf16 MFMA GEMM (32-row tiles), C[M][N] = A[M][K] @ Bw[N][K]^T (+bias).
//  stats_kernel (b x branch) + reduce_bn1: BN1 closed-form, per-block partials, no global atomics.
//  fused_layer2_dialog: ONE block per dialog, both branches: 20KB P/Q read -> 100x256 h1 tile
//    (bf16 LDS) -> 112x256 MFMA -> BN2 bins + anchor-row writes. 512 blocks = all resident.
//  finalize_bn2, postproc (bf16 msg/h0), GRU via gemm_mfma + elementwise.

typedef __attribute__((ext_vector_type(8))) short short8;
typedef __attribute__((ext_vector_type(4))) float f32x4;

__device__ __forceinline__ float softplusf(float x) {
  return x > 0.f ? x + log1pf(expf(-x)) : log1pf(expf(x));
}
__device__ __forceinline__ float wred64(float v) {
#pragma unroll
  for (int o = 32; o > 0; o >>= 1) v += __shfl_down(v, o);
  return v;
}
__device__ __forceinline__ unsigned short f2bf(float f) {
  unsigned int u = __float_as_uint(f);
  u += 0x7fffu + ((u >> 16) & 1u);
  return (unsigned short)(u >> 16);
}

// ---------------- prep: bf16 conversions ----------------
__global__ __launch_bounds__(256) void prep_weights(
    const float* __restrict__ utt,
    const float* __restrict__ a_w1, const float* __restrict__ s_w1,
    const float* __restrict__ a_w2, const float* __restrict__ s_w2,
    const float* __restrict__ gru_wi, const float* __restrict__ gru_wh,
    unsigned short* __restrict__ uttbf, unsigned short* __restrict__ Wcatbf,
    unsigned short* __restrict__ W2abf, unsigned short* __restrict__ W2sbf,
    unsigned short* __restrict__ wibf, unsigned short* __restrict__ whbf) {
  const int total = 2621440 + 524288 + 65536 + 65536 + 393216 + 196608;
  for (int idx = blockIdx.x * 256 + threadIdx.x; idx < total; idx += gridDim.x * 256) {
    int id = idx;
    if (id < 2621440) { uttbf[id] = f2bf(utt[id]); continue; }
    id -= 2621440;
    if (id < 524288) {  // Wcatbf[c][k], c<1024, k<512
      int c = id >> 9, k = id & 511;
      float v;
      if (c < 256)       v = a_w1[c * 1024 + k];
      else if (c < 512)  v = a_w1[(c - 256) * 1024 + 512 + k];
      else if (c < 768)  v = s_w1[(c - 512) * 1024 + k];
      else               v = s_w1[(c - 768) * 1024 + 512 + k];
      Wcatbf[id] = f2bf(v); continue;
    }
    id -= 524288;
    if (id < 65536) { W2abf[id] = f2bf(a_w2[id]); continue; }
    id -= 65536;
    if (id < 65536) { W2sbf[id] = f2bf(s_w2[id]); continue; }
    id -= 65536;
    if (id < 393216) { wibf[id] = f2bf(gru_wi[id]); continue; }
    id -= 393216;
    whbf[id] = f2bf(gru_wh[id]);
  }
}

// ---------------- generic MFMA GEMM (32-row tiles): C[M][N] = A[M][K] @ Bw[N][K]^T ----------------
// grid: (M/32, ceil(N/256)); 4 waves, wave w owns 64 cols.
__global__ __launch_bounds__(256) void gemm_mfma(
    const unsigned short* __restrict__ A, const unsigned short* __restrict__ Bw,
    float* __restrict__ C, const float* __restrict__ bias, int K, int N) {
  int t = threadIdx.x;
  int w = t >> 6, l = t & 63, li = l & 15, lg = l >> 4;
  int rowBase = blockIdx.x * 32;
  int colBase = blockIdx.y * 256 + w * 64;
  f32x4 acc[2][4] = {};
  const unsigned short* Arow[2];
  const unsigned short* Brow[4];
#pragma unroll
  for (int fr = 0; fr < 2; ++fr) Arow[fr] = A + (rowBase + fr * 16 + li) * K;
#pragma unroll
  for (int cf = 0; cf < 4; ++cf) Brow[cf] = Bw + (colBase + cf * 16 + li) * K;
  for (int ks = 0; ks < K / 32; ++ks) {
    int ka = ks * 32 + lg * 8;
    short8 afr[2], bfr[4];
#pragma unroll
    for (int fr = 0; fr < 2; ++fr) afr[fr] = *(const short8*)&Arow[fr][ka];
#pragma unroll
    for (int cf = 0; cf < 4; ++cf) bfr[cf] = *(const short8*)&Brow[cf][ka];
#pragma unroll
    for (int fr = 0; fr < 2; ++fr)
#pragma unroll
      for (int cf = 0; cf < 4; ++cf)
        acc[fr][cf] = __builtin_amdgcn_mfma_f32_16x16x32_bf16(afr[fr], bfr[cf], acc[fr][cf], 0, 0, 0);
  }
  float b2v[4] = {0.f, 0.f, 0.f, 0.f};
  if (bias) {
#pragma unroll
    for (int cf = 0; cf < 4; ++cf) b2v[cf] = bias[colBase + cf * 16 + li];
  }
#pragma unroll
  for (int fr = 0; fr < 2; ++fr)
#pragma unroll
    for (int reg = 0; reg < 4; ++reg) {
      int r = rowBase + fr * 16 + lg * 4 + reg;
      float* crow = C + r * N + colBase + li;
#pragma unroll
      for (int cf = 0; cf < 4; ++cf) crow[cf * 16] = acc[fr][cf][reg] + b2v[cf];
    }
}

// ---------------- BN1 stats: one block per (dialog, branch), per-block partials ----------------
__global__ __launch_bounds__(256) void stats_kernel(
    const float* __restrict__ PQ, const float* __restrict__ a_b1,
    const float* __restrict__ s_b1, float* __restrict__ Part) {
  __shared__ float lbins[4][32];
  int b = blockIdx.x, br = blockIdx.y, t = threadIdx.x;
  int w = t >> 6, l = t & 63;
  const float* base = PQ + b * 10240 + (br ? 512 : 0);
  const float* b1 = br ? s_b1 : a_b1;
  float P[10], Q[10];
#pragma unroll
  for (int j = 0; j < 10; ++j) Q[j] = base[j * 1024 + 256 + t];
#pragma unroll
  for (int i = 0; i < 10; ++i) P[i] = base[i * 1024 + t];
  float sq = 0.f, sq2 = 0.f;
#pragma unroll
  for (int j = 0; j < 10; ++j) { sq += Q[j]; sq2 += Q[j] * Q[j]; }
  float qbar = sq * 0.1f;
  float bb1 = b1[t];
  float r;
  r = wred64(sq);  if (l == 0) lbins[w][0] = r;
  r = wred64(sq2); if (l == 0) lbins[w][1] = r;
#pragma unroll
  for (int i = 0; i < 10; ++i) {
    float a = P[i] + bb1;
    r = wred64(P[i]);     if (l == 0) lbins[w][2 + i * 3] = r;
    r = wred64(a * a);    if (l == 0) lbins[w][3 + i * 3] = r;
    r = wred64(a * qbar); if (l == 0) lbins[w][4 + i * 3] = r;
  }
  __syncthreads();
  if (t < 32) Part[(b * 2 + br) * 32 + t] = lbins[0][t] + lbins[1][t] + lbins[2][t] + lbins[3][t];
}

// ---------------- reduce partials + BN1 closed-form finalize (grid = 2 branches) ----------------
__global__ void reduce_bn1(const float* __restrict__ Part,
                           const float* __restrict__ a_b1, const float* __restrict__ s_b1,
                           const float* __restrict__ a_g1, const float* __restrict__ a_be1,
                           const float* __restrict__ s_g1, const float* __restrict__ s_be1,
                           float* __restrict__ ST) {
  __shared__ float tmp[256];
  __shared__ float mom[32];
  int br = blockIdx.x, t = threadIdx.x;
  int v = t & 31, c = t >> 5;
  float s = 0.f;
  for (int b = c * 64; b < c * 64 + 64; ++b) s += Part[(b * 2 + br) * 32 + v];
  tmp[t] = s;
  __syncthreads();
  if (t < 32) {
    float m = 0.f;
#pragma unroll
    for (int k = 0; k < 8; ++k) m += tmp[k * 32 + t];
    mom[t] = m;
  }
  __syncthreads();
  if (t < 10) {
    int i = t;
    const float* b1 = br ? s_b1 : a_b1;
    float bsum = 0.f;
    for (int h = 0; h < 256; ++h) bsum += b1[h];
    float meanb1 = bsum * (1.f / 256.f);
    const float invBH = 1.f / (512.f * 256.f);
    const float invBLH = 1.f / (512.f * 10.f * 256.f);
    float SP = mom[2 + i * 3], SA2 = mom[3 + i * 3], SPQ = mom[4 + i * 3];
    float SQ = mom[0], SQ2 = mom[1];
    float mean = SP * invBH + meanb1 + SQ * invBLH;
    float Ez2 = SA2 * invBH + 2.f * SPQ * invBH + SQ2 * invBLH;
    float var = Ez2 - mean * mean;
    float g = br ? s_g1[i] : a_g1[i];
    float be = br ? s_be1[i] : a_be1[i];
    float sc = g / sqrtf(var + 1e-5f);
    ST[64 + br * 20 + i] = sc;
    ST[64 + br * 20 + 10 + i] = be - mean * sc;
  }
}

// ---------------- fused layer2, per-dialog block, both branches ----------------
template <int ACT>
__device__ __forceinline__ void do_branch(
    int b, int t, int anc,
    const float* __restrict__ PQ, int p_off,
    const float* __restrict__ b1, const float* __restrict__ ST, int sc_off,
    const unsigned short* __restrict__ W2bf, const float* __restrict__ b2,
    float* __restrict__ Z2out, float* binS, float* binQ,
    unsigned short (*Atile)[264]) {
  // ---- h1 phase: thread t = column c; 20 coalesced loads -> 100 h1 values ----
  {
    int c = t;
    float b1c = b1[c];
    float P[10], Q[10];
#pragma unroll
    for (int j = 0; j < 10; ++j) Q[j] = PQ[(b * 10 + j) * 1024 + p_off + 256 + c];
#pragma unroll
    for (int i = 0; i < 10; ++i) P[i] = PQ[(b * 10 + i) * 1024 + p_off + c];
#pragma unroll
    for (int i = 0; i < 10; ++i) {
      float sc = ST[sc_off + i], sh = ST[sc_off + 10 + i];
      float base = (P[i] + b1c) * sc + sh;
#pragma unroll
      for (int j = 0; j < 10; ++j) {
        float z = base + Q[j] * sc;
        float h;
        if (ACT) {
          float ex = __expf(2.f * z);
          h = (ex - 1.f) / (ex + 1.f);
        } else {
          h = fmaxf(z, 0.f);
        }
        Atile[i * 10 + j][c] = f2bf(h);
      }
    }
  }
  __syncthreads();
  // ---- MFMA: wave w owns 64 cols, all 112 rows ----
  int w = t >> 6, l = t & 63, li = l & 15, lg = l >> 4;
  int colBase = w * 64;
  f32x4 acc[7][4] = {};
  for (int ks = 0; ks < 8; ++ks) {
    int ka = ks * 32 + lg * 8;
    short8 bfr[4];
#pragma unroll
    for (int cf = 0; cf < 4; ++cf)
      bfr[cf] = *(const short8*)&W2bf[(colBase + cf * 16 + li) * 256 + ka];
#pragma unroll
    for (int fr = 0; fr < 7; ++fr) {
      short8 afr = *(const short8*)&Atile[fr * 16 + li][ka];
#pragma unroll
      for (int cf = 0; cf < 4; ++cf)
        acc[fr][cf] = __builtin_amdgcn_mfma_f32_16x16x32_bf16(afr, bfr[cf], acc[fr][cf], 0, 0, 0);
    }
  }
  // ---- epilogue: bias, anchor-row writes, BN2 bins ----
  float b2v[4];
#pragma unroll
  for (int cf = 0; cf < 4; ++cf) b2v[cf] = b2[colBase + cf * 16 + li];
#pragma unroll
  for (int fr = 0; fr < 7; ++fr) {
#pragma unroll
    for (int reg = 0; reg < 4; ++reg) {
      int row = fr * 16 + lg * 4 + reg;
      bool valid = row < 100;
      int ii = row / 10, jj = row - ii * 10;
      float z0 = acc[fr][0][reg] + b2v[0];
      float z1 = acc[fr][1][reg] + b2v[1];
      float z2 = acc[fr][2][reg] + b2v[2];
      float z3 = acc[fr][3][reg] + b2v[3];
      if (valid && ii == anc) {
        float* dst = Z2out + (b * 10 + jj) * 256 + colBase + li;
        dst[0] = z0; dst[16] = z1; dst[32] = z2; dst[48] = z3;
      }
      float s = valid ? (z0 + z1 + z2 + z3) : 0.f;
      float q = valid ? (z0 * z0 + z1 * z1 + z2 * z2 + z3 * z3) : 0.f;
#pragma unroll
      for (int o = 1; o < 16; o <<= 1) {
        s += __shfl_xor(s, o);
        q += __shfl_xor(q, o);
      }
      if (li == 0 && valid) {
        atomicAdd(&binS[ii], s);
        atomicAdd(&binQ[ii], q);
      }
    }
  }
}

__global__ __launch_bounds__(256, 2) void fused_layer2_dialog(
    const float* __restrict__ PQ, float* __restrict__ ST,
    const float* __restrict__ a_b1, const float* __restrict__ s_b1,
    const unsigned short* __restrict__ W2abf, const unsigned short* __restrict__ W2sbf,
    const float* __restrict__ a_b2, const float* __restrict__ s_b2,
    const int* __restrict__ cl, float* __restrict__ Z2a, float* __restrict__ Z2s) {
  __shared__ __align__(16) unsigned short Atile[112][264];
  __shared__ float bins[40];
  int b = blockIdx.x, t = threadIdx.x;
  int anc = cl[b] - 1;
  if (t < 40) bins[t] = 0.f;
  // zero pad rows 100..111
  for (int idx = t; idx < 12 * 264; idx += 256) (&Atile[100][0])[idx] = 0;
  do_branch<0>(b, t, anc, PQ, 0, a_b1, ST, 64, W2abf, a_b2, Z2a, bins + 0, bins + 10, Atile);
  __syncthreads();  // Atile reads + A-bins done before S overwrites
  if (t < 10) {
    atomicAdd(&ST[104 + t], bins[t]);
    atomicAdd(&ST[114 + t], bins[10 + t]);
  }
  do_branch<1>(b, t, anc, PQ, 512, s_b1, ST, 84, W2sbf, s_b2, Z2s, bins + 20, bins + 30, Atile);
  __syncthreads();
  if (t < 10) {
    atomicAdd(&ST[124 + t], bins[20 + t]);
    atomicAdd(&ST[134 + t], bins[30 + t]);
  }
}

// ---------------- BN2 finalize ----------------
__global__ void finalize_bn2(const float* __restrict__ a_g2, const float* __restrict__ a_be2,
                             const float* __restrict__ s_g2, const float* __restrict__ s_be2,
                             float* __restrict__ ST) {
  int t = threadIdx.x;
  if (t >= 20) return;
  int br = t / 10, i = t % 10;
  const float invN = 1.f / (512.f * 10.f * 256.f);
  float m = ST[104 + br * 20 + i] * invN;
  float v = ST[104 + br * 20 + 10 + i] * invN - m * m;
  float g = br ? s_g2[i] : a_g2[i];
  float be = br ? s_be2[i] : a_be2[i];
  float sc = g / sqrtf(v + 1e-5f);
  ST[144 + br * 20 + i] = sc;
  ST[144 + br * 20 + 10 + i] = be - m * sc;
}

// ---------------- postproc ----------------
__global__ __launch_bounds__(256) void postproc_kernel(
    const float* __restrict__ Z2a, const float* __restrict__ Z2s, const float* __restrict__ ST,
    const float* __restrict__ a_w3, const float* __restrict__ a_b3,
    const float* __restrict__ mu_w, const float* __restrict__ mu_b,
    const float* __restrict__ sg_w, const float* __restrict__ sg_b,
    const float* __restrict__ aij_eps, const float* __restrict__ sij_eps,
    const int* __restrict__ cl, const float* __restrict__ utt,
    unsigned short* __restrict__ msgbf, unsigned short* __restrict__ h0bf,
    float* __restrict__ h0out) {
  int b = blockIdx.x, t = threadIdx.x;
  int a = cl[b] - 1;
  float sc2a = ST[144 + a], sh2a = ST[154 + a];
  float sc2s = ST[164 + a], sh2s = ST[174 + a];
  float w3 = a_w3[t], mw = mu_w[t], sw = sg_w[t];
  __shared__ float red[30];
  if (t < 30) red[t] = 0.f;
  __syncthreads();
#pragma unroll
  for (int j = 0; j < 10; ++j) {
    float za = Z2a[(b * 10 + j) * 256 + t];
    float va = fmaxf(za * sc2a + sh2a, 0.f);
    float zs = Z2s[(b * 10 + j) * 256 + t];
    float vs = tanhf(zs * sc2s + sh2s);
    float pa = wred64(va * w3);
    float pm = wred64(vs * mw);
    float ps = wred64(vs * sw);
    if ((t & 63) == 0) {
      atomicAdd(&red[j], pa);
      atomicAdd(&red[10 + j], pm);
      atomicAdd(&red[20 + j], ps);
    }
  }
  __syncthreads();
  __shared__ float pw[10];
  __shared__ float wijs[16];
  if (t < 10) {
    int j = t;
    float amij = red[j] + a_b3[0];
    float amu = softplusf(amij) + 0.01f;
    float astd = sqrtf(softplusf((1.f - amu) * amu) + 0.01f);
    float ae = aij_eps[b * 100 + a * 10 + j];
    float aij = softplusf(ae * astd + amu) + 0.01f;
    float smu = red[10 + j] + mu_b[0];
    float ssg = red[20 + j] + sg_b[0];
    float se = sij_eps[b * 100 + a * 10 + j];
    float sij = se * sqrtf(aij * ssg * ssg) + aij * smu;
    wijs[j] = aij * sij;
  }
  __syncthreads();
  if (t == 0) {
    float mx = -1e30f;
    for (int j = 0; j < a; ++j) mx = fmaxf(mx, wijs[j]);
    float e[10];
    float den = 0.f;
    for (int j = 0; j < a; ++j) { e[j] = expf(wijs[j] - mx); den += e[j]; }
    for (int j = 0; j < 10; ++j) pw[j] = (j < a) ? e[j] / den : 0.f;
  }
  __syncthreads();
#pragma unroll
  for (int dd = 0; dd < 2; ++dd) {
    int d = t + dd * 256;
    float mv = 0.f;
#pragma unroll
    for (int j = 0; j < 10; ++j) mv += pw[j] * utt[(b * 10 + j) * 512 + d];
    msgbf[b * 512 + d] = f2bf(mv);
  }
  float u1 = utt[(b * 10 + a) * 512 + t];
  float u2 = utt[(b * 10 + a) * 512 + 256 + t];
  float h0v = u1 + u2;
  h0out[b * 256 + t] = h0v;
  h0bf[b * 256 + t] = f2bf(h0v);
}

// ---------------- GRU elementwise ----------------
__global__ __launch_bounds__(256) void gru_final(const float* __restrict__ gi,
                                                 const float* __restrict__ gh,
                                                 const float* __restrict__ h0,
                                                 float* __restrict__ out) {
  int idx = blockIdx.x * 256 + threadIdx.x;
  int b = idx >> 8, h = idx & 255;
  float ir = gi[b * 768 + h], iz = gi[b * 768 + 256 + h], inn = gi[b * 768 + 512 + h];
  float hr = gh[b * 768 + h], hz = gh[b * 768 + 256 + h], hn = gh[b * 768 + 512 + h];
  float r = 1.f / (1.f + expf(-(ir + hr)));
  float z = 1.f / (1.f + expf(-(iz + hz)));
  float n = tanhf(inn + r * hn);
  out[idx] = (1.f - z) * n + z * h0[b * 256 + h];
}

extern "C" void kernel_launch(void* const* d_in, const int* in_sizes, int n_in,
                              void* d_out, int out_size, void* d_ws, size_t ws_size,
                              hipStream_t stream) {
  const float* utt = (const float*)d_in[0];
  const float* aij_eps = (const float*)d_in[1];
  const float* sij_eps = (const float*)d_in[2];
  const int* cl = (const int*)d_in[3];
  const float* a_w1 = (const float*)d_in[4];
  const float* a_b1 = (const float*)d_in[5];
  const float* a_g1 = (const float*)d_in[6];
  const float* a_be1 = (const float*)d_in[7];
  const float* a_w2 = (const float*)d_in[8];
  const float* a_b2 = (const float*)d_in[9];
  const float* a_g2 = (const float*)d_in[10];
  const float* a_be2 = (const float*)d_in[11];
  const float* a_w3 = (const float*)d_in[12];
  const float* a_b3 = (const float*)d_in[13];
  const float* s_w1 = (const float*)d_in[14];
  const float* s_b1 = (const float*)d_in[15];
  const float* s_g1 = (const float*)d_in[16];
  const float* s_be1 = (const float*)d_in[17];
  const float* s_w2 = (const float*)d_in[18];
  const float* s_b2 = (const float*)d_in[19];
  const float* s_g2 = (const float*)d_in[20];
  const float* s_be2 = (const float*)d_in[21];
  const float* mu_w = (const float*)d_in[22];
  const float* mu_b = (const float*)d_in[23];
  const float* sg_w = (const float*)d_in[24];
  const float* sg_b = (const float*)d_in[25];
  const float* gru_wi = (const float*)d_in[26];
  const float* gru_wh = (const float*)d_in[27];
  const float* gru_bi = (const float*)d_in[28];
  const float* gru_bh = (const float*)d_in[29];

  float* ws = (float*)d_ws;
  float* ST = ws;                                            // 256 floats
  unsigned short* uttbf = (unsigned short*)(ws + 256);       // 2621440 sh
  unsigned short* Wcatbf = uttbf + 2621440;                  // 524288 sh
  unsigned short* W2abf = Wcatbf + 524288;                   // 65536 sh
  unsigned short* W2sbf = W2abf + 65536;                     // 65536 sh
  unsigned short* wibf = W2sbf + 65536;                      // 393216 sh
  unsigned short* whbf = wibf + 393216;                      // 196608 sh
  float* PQ = (float*)(whbf + 196608);                       // 5242880 f
  float* Z2a = PQ + 5242880;                                 // 1310720 f
  float* Z2s = Z2a + 1310720;                                // 1310720 f
  float* Part = Z2s + 1310720;                               // 32768 f
  // postproc/GRU buffers alias PQ (dead after fused_layer2_dialog)
  unsigned short* msgbf = (unsigned short*)PQ;               // 262144 sh
  unsigned short* h0bf = msgbf + 262144;                     // 131072 sh
  float* h0 = PQ + 196608;                                   // 131072 f
  float* gi = PQ + 327680;                                   // 393216 f
  float* gh = gi + 393216;                                   // 393216 f

  hipMemsetAsync(ST, 0, 256 * sizeof(float), stream);
  prep_weights<<<1024, 256, 0, stream>>>(utt, a_w1, s_w1, a_w2, s_w2, gru_wi, gru_wh,
                                         uttbf, Wcatbf, W2abf, W2sbf, wibf, whbf);
  gemm_mfma<<<dim3(160, 4), 256, 0, stream>>>(uttbf, Wcatbf, PQ, nullptr, 512, 1024);
  stats_kernel<<<dim3(512, 2), 256, 0, stream>>>(PQ, a_b1, s_b1, Part);
  reduce_bn1<<<2, 256, 0, stream>>>(Part, a_b1, s_b1, a_g1, a_be1, s_g1, s_be1, ST);
  fused_layer2_dialog<<<512, 256, 0, stream>>>(PQ, ST, a_b1, s_b1, W2abf, W2sbf,
                                               a_b2, s_b2, cl, Z2a, Z2s);
  finalize_bn2<<<1, 32, 0, stream>>>(a_g2, a_be2, s_g2, s_be2, ST);
  postproc_kernel<<<512, 256, 0, stream>>>(Z2a, Z2s, ST, a_w3, a_b3, mu_w, mu_b, sg_w, sg_b,
                                           aij_eps, sij_eps, cl, utt, msgbf, h0bf, h0);
  gemm_mfma<<<dim3(16, 3), 256, 0, stream>>>(msgbf, wibf, gi, gru_bi, 512, 768);
  gemm_mfma<<<dim3(16, 3), 256, 0, stream>>>(h0bf, whbf, gh, gru_bh, 256, 768);
  gru_final<<<512, 256, 0, stream>>>(gi, gh, h0, (float*)d_out);
}

// Round 7
// 166.138 us; speedup vs baseline: 3.8947x; 1.2267x over previous
//
#include <hip/hip_runtime.h>
#include <math.h>

// ContextEncoder: B=512, L=10, H=256, D=512.
//  prep: bf16 conversions; A/B/W2 written in MFMA *fragment order* (coalesced 1KB frag loads).
//  gemm_pq_swz: PQ[5120][1024] = utt @ Wcat^T, swizzled operands, reg double-buffered k-loop.
//  stats_kernel + reduce_bn1: BN1 closed-form from P/Q moments, per-block partials.
//  fused_layer2_half: grid (512 dialogs x 2 halves x 2 branches). Per block: 15KB P/Q read ->
//    50x256 h1 (bf16 LDS) -> 64x256 MFMA (coalesced W2 frags, prefetched) -> BN2 bins + anchor rows.
//    33KB LDS -> 4 blocks/CU.
//  finalize_bn2, postproc (bf16 msg/h0), GRU via generic gemm_mfma + elementwise.

typedef __attribute__((ext_vector_type(8))) short short8;
typedef __attribute__((ext_vector_type(4))) float f32x4;

__device__ __forceinline__ float softplusf(float x) {
  return x > 0.f ? x + log1pf(expf(-x)) : log1pf(expf(x));
}
__device__ __forceinline__ float wred64(float v) {
#pragma unroll
  for (int o = 32; o > 0; o >>= 1) v += __shfl_down(v, o);
  return v;
}
__device__ __forceinline__ unsigned short f2bf(float f) {
  unsigned int u = __float_as_uint(f);
  u += 0x7fffu + ((u >> 16) & 1u);
  return (unsigned short)(u >> 16);
}

// ---------------- prep: bf16 conversions + fragment-order swizzles ----------------
// Af[rb][ks][lane][e]: row=rb*16+(lane&15), k=ks*32+(lane>>4)*8+e   (rb<320: id>>13, ks: (id>>9)&15)
// Bf[cb][ks][cf][lane][e]: col=cb*64+cf*16+(lane&15), k=ks*32+(lane>>4)*8+e (cb<16, ks<16)
// W2f[cb][ks][cf][lane][e]: col=cb*64+cf*16+(lane&15), k=ks*32+(lane>>4)*8+e (cb<4, ks<8)
__global__ __launch_bounds__(256) void prep_weights(
    const float* __restrict__ utt,
    const float* __restrict__ a_w1, const float* __restrict__ s_w1,
    const float* __restrict__ a_w2, const float* __restrict__ s_w2,
    const float* __restrict__ gru_wi, const float* __restrict__ gru_wh,
    unsigned short* __restrict__ Af, unsigned short* __restrict__ Bf,
    unsigned short* __restrict__ W2fa, unsigned short* __restrict__ W2fs,
    unsigned short* __restrict__ wibf, unsigned short* __restrict__ whbf) {
  const int total = 2621440 + 524288 + 65536 + 65536 + 393216 + 196608;
  for (int idx = blockIdx.x * 256 + threadIdx.x; idx < total; idx += gridDim.x * 256) {
    int id = idx;
    if (id < 2621440) {  // Af: id = rb*8192 + ks*512 + lane*8 + e
      int e = id & 7, lane = (id >> 3) & 63, ks = (id >> 9) & 15, rb = id >> 13;
      int row = rb * 16 + (lane & 15);
      int k = ks * 32 + (lane >> 4) * 8 + e;
      Af[id] = f2bf(utt[row * 512 + k]); continue;
    }
    id -= 2621440;
    if (id < 524288) {  // Bf: id = cb*32768 + ks*2048 + cf*512 + lane*8 + e
      int e = id & 7, lane = (id >> 3) & 63, cf = (id >> 9) & 3, ks = (id >> 11) & 15, cb = id >> 15;
      int c = cb * 64 + cf * 16 + (lane & 15);
      int k = ks * 32 + (lane >> 4) * 8 + e;
      float v;
      if (c < 256)       v = a_w1[c * 1024 + k];
      else if (c < 512)  v = a_w1[(c - 256) * 1024 + 512 + k];
      else if (c < 768)  v = s_w1[(c - 512) * 1024 + k];
      else               v = s_w1[(c - 768) * 1024 + 512 + k];
      Bf[id] = f2bf(v); continue;
    }
    id -= 524288;
    if (id < 65536) {  // W2fa: id = cb*16384 + ks*2048 + cf*512 + lane*8 + e
      int e = id & 7, lane = (id >> 3) & 63, cf = (id >> 9) & 3, ks = (id >> 11) & 7, cb = id >> 14;
      int c = cb * 64 + cf * 16 + (lane & 15);
      int k = ks * 32 + (lane >> 4) * 8 + e;
      W2fa[id] = f2bf(a_w2[c * 256 + k]); continue;
    }
    id -= 65536;
    if (id < 65536) {  // W2fs
      int e = id & 7, lane = (id >> 3) & 63, cf = (id >> 9) & 3, ks = (id >> 11) & 7, cb = id >> 14;
      int c = cb * 64 + cf * 16 + (lane & 15);
      int k = ks * 32 + (lane >> 4) * 8 + e;
      W2fs[id] = f2bf(s_w2[c * 256 + k]); continue;
    }
    id -= 65536;
    if (id < 393216) { wibf[id] = f2bf(gru_wi[id]); continue; }
    id -= 393216;
    whbf[id] = f2bf(gru_wh[id]);
  }
}

// ---------------- PQ GEMM, swizzled operands, reg double-buffer ----------------
// grid (160, 4): block = 32 rows x 256 cols, K=512.
__global__ __launch_bounds__(256, 4) void gemm_pq_swz(
    const unsigned short* __restrict__ Af, const unsigned short* __restrict__ Bf,
    float* __restrict__ C) {
  int t = threadIdx.x;
  int w = t >> 6, l = t & 63, li = l & 15, lg = l >> 4;
  int rb0 = blockIdx.x * 2;
  int cb = blockIdx.y * 4 + w;
  const unsigned short* Bb = Bf + cb * (16 * 4 * 512);
  f32x4 acc[2][4] = {};
  short8 acur[2], bcur[4], anxt[2], bnxt[4];
#pragma unroll
  for (int fr = 0; fr < 2; ++fr) acur[fr] = *(const short8*)&Af[((rb0 + fr) * 16 + 0) * 512 + l * 8];
#pragma unroll
  for (int cf = 0; cf < 4; ++cf) bcur[cf] = *(const short8*)&Bb[(0 * 4 + cf) * 512 + l * 8];
  for (int ks = 0; ks < 16; ++ks) {
    if (ks < 15) {
#pragma unroll
      for (int fr = 0; fr < 2; ++fr) anxt[fr] = *(const short8*)&Af[((rb0 + fr) * 16 + ks + 1) * 512 + l * 8];
#pragma unroll
      for (int cf = 0; cf < 4; ++cf) bnxt[cf] = *(const short8*)&Bb[((ks + 1) * 4 + cf) * 512 + l * 8];
    }
#pragma unroll
    for (int fr = 0; fr < 2; ++fr)
#pragma unroll
      for (int cf = 0; cf < 4; ++cf)
        acc[fr][cf] = __builtin_amdgcn_mfma_f32_16x16x32_bf16(acur[fr], bcur[cf], acc[fr][cf], 0, 0, 0);
#pragma unroll
    for (int fr = 0; fr < 2; ++fr) acur[fr] = anxt[fr];
#pragma unroll
    for (int cf = 0; cf < 4; ++cf) bcur[cf] = bnxt[cf];
  }
  int rowBase = blockIdx.x * 32, colBase = cb * 64;
#pragma unroll
  for (int fr = 0; fr < 2; ++fr)
#pragma unroll
    for (int reg = 0; reg < 4; ++reg) {
      int r = rowBase + fr * 16 + lg * 4 + reg;
      float* crow = C + r * 1024 + colBase + li;
#pragma unroll
      for (int cf = 0; cf < 4; ++cf) crow[cf * 16] = acc[fr][cf][reg];
    }
}

// ---------------- BN1 stats: one block per (dialog, branch), per-block partials ----------------
__global__ __launch_bounds__(256) void stats_kernel(
    const float* __restrict__ PQ, const float* __restrict__ a_b1,
    const float* __restrict__ s_b1, float* __restrict__ Part) {
  __shared__ float lbins[4][32];
  int b = blockIdx.x, br = blockIdx.y, t = threadIdx.x;
  int w = t >> 6, l = t & 63;
  const float* base = PQ + b * 10240 + (br ? 512 : 0);
  const float* b1 = br ? s_b1 : a_b1;
  float P[10], Q[10];
#pragma unroll
  for (int j = 0; j < 10; ++j) Q[j] = base[j * 1024 + 256 + t];
#pragma unroll
  for (int i = 0; i < 10; ++i) P[i] = base[i * 1024 + t];
  float sq = 0.f, sq2 = 0.f;
#pragma unroll
  for (int j = 0; j < 10; ++j) { sq += Q[j]; sq2 += Q[j] * Q[j]; }
  float qbar = sq * 0.1f;
  float bb1 = b1[t];
  float r;
  r = wred64(sq);  if (l == 0) lbins[w][0] = r;
  r = wred64(sq2); if (l == 0) lbins[w][1] = r;
#pragma unroll
  for (int i = 0; i < 10; ++i) {
    float a = P[i] + bb1;
    r = wred64(P[i]);     if (l == 0) lbins[w][2 + i * 3] = r;
    r = wred64(a * a);    if (l == 0) lbins[w][3 + i * 3] = r;
    r = wred64(a * qbar); if (l == 0) lbins[w][4 + i * 3] = r;
  }
  __syncthreads();
  if (t < 32) Part[(b * 2 + br) * 32 + t] = lbins[0][t] + lbins[1][t] + lbins[2][t] + lbins[3][t];
}

// ---------------- reduce partials + BN1 closed-form finalize (grid = 2 branches) ----------------
__global__ void reduce_bn1(const float* __restrict__ Part,
                           const float* __restrict__ a_b1, const float* __restrict__ s_b1,
                           const float* __restrict__ a_g1, const float* __restrict__ a_be1,
                           const float* __restrict__ s_g1, const float* __restrict__ s_be1,
                           float* __restrict__ ST) {
  __shared__ float tmp[256];
  __shared__ float mom[32];
  int br = blockIdx.x, t = threadIdx.x;
  int v = t & 31, c = t >> 5;
  float s = 0.f;
  for (int b = c * 64; b < c * 64 + 64; ++b) s += Part[(b * 2 + br) * 32 + v];
  tmp[t] = s;
  __syncthreads();
  if (t < 32) {
    float m = 0.f;
#pragma unroll
    for (int k = 0; k < 8; ++k) m += tmp[k * 32 + t];
    mom[t] = m;
  }
  __syncthreads();
  if (t < 10) {
    int i = t;
    const float* b1 = br ? s_b1 : a_b1;
    float bsum = 0.f;
    for (int h = 0; h < 256; ++h) bsum += b1[h];
    float meanb1 = bsum * (1.f / 256.f);
    const float invBH = 1.f / (512.f * 256.f);
    const float invBLH = 1.f / (512.f * 10.f * 256.f);
    float SP = mom[2 + i * 3], SA2 = mom[3 + i * 3], SPQ = mom[4 + i * 3];
    float SQ = mom[0], SQ2 = mom[1];
    float mean = SP * invBH + meanb1 + SQ * invBLH;
    float Ez2 = SA2 * invBH + 2.f * SPQ * invBH + SQ2 * invBLH;
    float var = Ez2 - mean * mean;
    float g = br ? s_g1[i] : a_g1[i];
    float be = br ? s_be1[i] : a_be1[i];
    float sc = g / sqrtf(var + 1e-5f);
    ST[64 + br * 20 + i] = sc;
    ST[64 + br * 20 + 10 + i] = be - mean * sc;
  }
}

// ---------------- fused layer2: block = (dialog, i-half, branch) ----------------
__global__ __launch_bounds__(256, 4) void fused_layer2_half(
    const float* __restrict__ PQ, float* __restrict__ ST,
    const float* __restrict__ a_b1, const float* __restrict__ s_b1,
    const unsigned short* __restrict__ W2fa, const unsigned short* __restrict__ W2fs,
    const float* __restrict__ a_b2, const float* __restrict__ s_b2,
    const int* __restrict__ cl, float* __restrict__ Z2a, float* __restrict__ Z2s) {
  __shared__ __align__(16) unsigned short Atile[64][264];
  __shared__ float bins[10];
  int b = blockIdx.x, half = blockIdx.y, br = blockIdx.z;
  int i0 = half * 5;
  int p_off = br ? 512 : 0;
  const float* b1 = br ? s_b1 : a_b1;
  const unsigned short* W2f = br ? W2fs : W2fa;
  const float* b2 = br ? s_b2 : a_b2;
  float* Z2out = br ? Z2s : Z2a;
  int sc_off = br ? 84 : 64;
  int t = threadIdx.x;
  int anc = cl[b] - 1;
  if (t < 10) bins[t] = 0.f;
  for (int idx = t; idx < 14 * 264; idx += 256) (&Atile[50][0])[idx] = 0;
  // ---- h1 phase: thread t = column c; 15 coalesced loads -> 50 h1 values ----
  {
    int c = t;
    float b1c = b1[c];
    float P[5], Q[10];
#pragma unroll
    for (int j = 0; j < 10; ++j) Q[j] = PQ[(b * 10 + j) * 1024 + p_off + 256 + c];
#pragma unroll
    for (int il = 0; il < 5; ++il) P[il] = PQ[(b * 10 + i0 + il) * 1024 + p_off + c];
#pragma unroll
    for (int il = 0; il < 5; ++il) {
      float sc = ST[sc_off + i0 + il], sh = ST[sc_off + 10 + i0 + il];
      float base = (P[il] + b1c) * sc + sh;
#pragma unroll
      for (int j = 0; j < 10; ++j) {
        float z = base + Q[j] * sc;
        float h;
        if (br) {
          float ex = __expf(2.f * z);
          h = (ex - 1.f) / (ex + 1.f);
        } else {
          h = fmaxf(z, 0.f);
        }
        Atile[il * 10 + j][c] = f2bf(h);
      }
    }
  }
  __syncthreads();
  // ---- MFMA: wave w owns 64 cols, 64 rows (50 valid); W2 frags coalesced + prefetched ----
  int w = t >> 6, l = t & 63, li = l & 15, lg = l >> 4;
  int colBase = w * 64;
  const unsigned short* Wb = W2f + w * (8 * 4 * 512);
  f32x4 acc[4][4] = {};
  short8 bcur[4], bnxt[4];
#pragma unroll
  for (int cf = 0; cf < 4; ++cf) bcur[cf] = *(const short8*)&Wb[(0 * 4 + cf) * 512 + l * 8];
  for (int ks = 0; ks < 8; ++ks) {
    if (ks < 7) {
#pragma unroll
      for (int cf = 0; cf < 4; ++cf) bnxt[cf] = *(const short8*)&Wb[((ks + 1) * 4 + cf) * 512 + l * 8];
    }
    int ka = ks * 32 + lg * 8;
#pragma unroll
    for (int fr = 0; fr < 4; ++fr) {
      short8 afr = *(const short8*)&Atile[fr * 16 + li][ka];
#pragma unroll
      for (int cf = 0; cf < 4; ++cf)
        acc[fr][cf] = __builtin_amdgcn_mfma_f32_16x16x32_bf16(afr, bcur[cf], acc[fr][cf], 0, 0, 0);
    }
#pragma unroll
    for (int cf = 0; cf < 4; ++cf) bcur[cf] = bnxt[cf];
  }
  // ---- epilogue: bias, anchor-row writes, BN2 bins ----
  float b2v[4];
#pragma unroll
  for (int cf = 0; cf < 4; ++cf) b2v[cf] = b2[colBase + cf * 16 + li];
#pragma unroll
  for (int fr = 0; fr < 4; ++fr) {
#pragma unroll
    for (int reg = 0; reg < 4; ++reg) {
      int row = fr * 16 + lg * 4 + reg;
      bool valid = row < 50;
      int il = row / 10, jj = row - il * 10;
      float z0 = acc[fr][0][reg] + b2v[0];
      float z1 = acc[fr][1][reg] + b2v[1];
      float z2 = acc[fr][2][reg] + b2v[2];
      float z3 = acc[fr][3][reg] + b2v[3];
      if (valid && (i0 + il) == anc) {
        float* dst = Z2out + (b * 10 + jj) * 256 + colBase + li;
        dst[0] = z0; dst[16] = z1; dst[32] = z2; dst[48] = z3;
      }
      float s = valid ? (z0 + z1 + z2 + z3) : 0.f;
      float q = valid ? (z0 * z0 + z1 * z1 + z2 * z2 + z3 * z3) : 0.f;
#pragma unroll
      for (int o = 1; o < 16; o <<= 1) {
        s += __shfl_xor(s, o);
        q += __shfl_xor(q, o);
      }
      if (li == 0 && valid) {
        atomicAdd(&bins[il], s);
        atomicAdd(&bins[5 + il], q);
      }
    }
  }
  __syncthreads();
  if (t < 5) {
    atomicAdd(&ST[104 + br * 20 + i0 + t], bins[t]);
    atomicAdd(&ST[104 + br * 20 + 10 + i0 + t], bins[5 + t]);
  }
}

// ---------------- BN2 finalize ----------------
__global__ void finalize_bn2(const float* __restrict__ a_g2, const float* __restrict__ a_be2,
                             const float* __restrict__ s_g2, const float* __restrict__ s_be2,
                             float* __restrict__ ST) {
  int t = threadIdx.x;
  if (t >= 20) return;
  int br = t / 10, i = t % 10;
  const float invN = 1.f / (512.f * 10.f * 256.f);
  float m = ST[104 + br * 20 + i] * invN;
  float v = ST[104 + br * 20 + 10 + i] * invN - m * m;
  float g = br ? s_g2[i] : a_g2[i];
  float be = br ? s_be2[i] : a_be2[i];
  float sc = g / sqrtf(v + 1e-5f);
  ST[144 + br * 20 + i] = sc;
  ST[144 + br * 20 + 10 + i] = be - m * sc;
}

// ---------------- generic MFMA GEMM (32-row tiles), for GRU ----------------
__global__ __launch_bounds__(256) void gemm_mfma(
    const unsigned short* __restrict__ A, const unsigned short* __restrict__ Bw,
    float* __restrict__ C, const float* __restrict__ bias, int K, int N) {
  int t = threadIdx.x;
  int w = t >> 6, l = t & 63, li = l & 15, lg = l >> 4;
  int rowBase = blockIdx.x * 32;
  int colBase = blockIdx.y * 256 + w * 64;
  f32x4 acc[2][4] = {};
  const unsigned short* Arow[2];
  const unsigned short* Brow[4];
#pragma unroll
  for (int fr = 0; fr < 2; ++fr) Arow[fr] = A + (rowBase + fr * 16 + li) * K;
#pragma unroll
  for (int cf = 0; cf < 4; ++cf) Brow[cf] = Bw + (colBase + cf * 16 + li) * K;
  for (int ks = 0; ks < K / 32; ++ks) {
    int ka = ks * 32 + lg * 8;
    short8 afr[2], bfr[4];
#pragma unroll
    for (int fr = 0; fr < 2; ++fr) afr[fr] = *(const short8*)&Arow[fr][ka];
#pragma unroll
    for (int cf = 0; cf < 4; ++cf) bfr[cf] = *(const short8*)&Brow[cf][ka];
#pragma unroll
    for (int fr = 0; fr < 2; ++fr)
#pragma unroll
      for (int cf = 0; cf < 4; ++cf)
        acc[fr][cf] = __builtin_amdgcn_mfma_f32_16x16x32_bf16(afr[fr], bfr[cf], acc[fr][cf], 0, 0, 0);
  }
  float b2v[4] = {0.f, 0.f, 0.f, 0.f};
  if (bias) {
#pragma unroll
    for (int cf = 0; cf < 4; ++cf) b2v[cf] = bias[colBase + cf * 16 + li];
  }
#pragma unroll
  for (int fr = 0; fr < 2; ++fr)
#pragma unroll
    for (int reg = 0; reg < 4; ++reg) {
      int r = rowBase + fr * 16 + lg * 4 + reg;
      float* crow = C + r * N + colBase + li;
#pragma unroll
      for (int cf = 0; cf < 4; ++cf) crow[cf * 16] = acc[fr][cf][reg] + b2v[cf];
    }
}

// ---------------- postproc ----------------
__global__ __launch_bounds__(256) void postproc_kernel(
    const float* __restrict__ Z2a, const float* __restrict__ Z2s, const float* __restrict__ ST,
    const float* __restrict__ a_w3, const float* __restrict__ a_b3,
    const float* __restrict__ mu_w, const float* __restrict__ mu_b,
    const float* __restrict__ sg_w, const float* __restrict__ sg_b,
    const float* __restrict__ aij_eps, const float* __restrict__ sij_eps,
    const int* __restrict__ cl, const float* __restrict__ utt,
    unsigned short* __restrict__ msgbf, unsigned short* __restrict__ h0bf,
    float* __restrict__ h0out) {
  int b = blockIdx.x, t = threadIdx.x;
  int a = cl[b] - 1;
  float sc2a = ST[144 + a], sh2a = ST[154 + a];
  float sc2s = ST[164 + a], sh2s = ST[174 + a];
  float w3 = a_w3[t], mw = mu_w[t], sw = sg_w[t];
  __shared__ float red[30];
  if (t < 30) red[t] = 0.f;
  __syncthreads();
#pragma unroll
  for (int j = 0; j < 10; ++j) {
    float za = Z2a[(b * 10 + j) * 256 + t];
    float va = fmaxf(za * sc2a + sh2a, 0.f);
    float zs = Z2s[(b * 10 + j) * 256 + t];
    float vs = tanhf(zs * sc2s + sh2s);
    float pa = wred64(va * w3);
    float pm = wred64(vs * mw);
    float ps = wred64(vs * sw);
    if ((t & 63) == 0) {
      atomicAdd(&red[j], pa);
      atomicAdd(&red[10 + j], pm);
      atomicAdd(&red[20 + j], ps);
    }
  }
  __syncthreads();
  __shared__ float pw[10];
  __shared__ float wijs[16];
  if (t < 10) {
    int j = t;
    float amij = red[j] + a_b3[0];
    float amu = softplusf(amij) + 0.01f;
    float astd = sqrtf(softplusf((1.f - amu) * amu) + 0.01f);
    float ae = aij_eps[b * 100 + a * 10 + j];
    float aij = softplusf(ae * astd + amu) + 0.01f;
    float smu = red[10 + j] + mu_b[0];
    float ssg = red[20 + j] + sg_b[0];
    float se = sij_eps[b * 100 + a * 10 + j];
    float sij = se * sqrtf(aij * ssg * ssg) + aij * smu;
    wijs[j] = aij * sij;
  }
  __syncthreads();
  if (t == 0) {
    float mx = -1e30f;
    for (int j = 0; j < a; ++j) mx = fmaxf(mx, wijs[j]);
    float e[10];
    float den = 0.f;
    for (int j = 0; j < a; ++j) { e[j] = expf(wijs[j] - mx); den += e[j]; }
    for (int j = 0; j < 10; ++j) pw[j] = (j < a) ? e[j] / den : 0.f;
  }
  __syncthreads();
#pragma unroll
  for (int dd = 0; dd < 2; ++dd) {
    int d = t + dd * 256;
    float mv = 0.f;
#pragma unroll
    for (int j = 0; j < 10; ++j) mv += pw[j] * utt[(b * 10 + j) * 512 + d];
    msgbf[b * 512 + d] = f2bf(mv);
  }
  float u1 = utt[(b * 10 + a) * 512 + t];
  float u2 = utt[(b * 10 + a) * 512 + 256 + t];
  float h0v = u1 + u2;
  h0out[b * 256 + t] = h0v;
  h0bf[b * 256 + t] = f2bf(h0v);
}

// ---------------- GRU elementwise ----------------
__global__ __launch_bounds__(256) void gru_final(const float* __restrict__ gi,
                                                 const float* __restrict__ gh,
                                                 const float* __restrict__ h0,
                                                 float* __restrict__ out) {
  int idx = blockIdx.x * 256 + threadIdx.x;
  int b = idx >> 8, h = idx & 255;
  float ir = gi[b * 768 + h], iz = gi[b * 768 + 256 + h], inn = gi[b * 768 + 512 + h];
  float hr = gh[b * 768 + h], hz = gh[b * 768 + 256 + h], hn = gh[b * 768 + 512 + h];
  float r = 1.f / (1.f + expf(-(ir + hr)));
  float z = 1.f / (1.f + expf(-(iz + hz)));
  float n = tanhf(inn + r * hn);
  out[idx] = (1.f - z) * n + z * h0[b * 256 + h];
}

extern "C" void kernel_launch(void* const* d_in, const int* in_sizes, int n_in,
                              void* d_out, int out_size, void* d_ws, size_t ws_size,
                              hipStream_t stream) {
  const float* utt = (const float*)d_in[0];
  const float* aij_eps = (const float*)d_in[1];
  const float* sij_eps = (const float*)d_in[2];
  const int* cl = (const int*)d_in[3];
  const float* a_w1 = (const float*)d_in[4];
  const float* a_b1 = (const float*)d_in[5];
  const float* a_g1 = (const float*)d_in[6];
  const float* a_be1 = (const float*)d_in[7];
  const float* a_w2 = (const float*)d_in[8];
  const float* a_b2 = (const float*)d_in[9];
  const float* a_g2 = (const float*)d_in[10];
  const float* a_be2 = (const float*)d_in[11];
  const float* a_w3 = (const float*)d_in[12];
  const float* a_b3 = (const float*)d_in[13];
  const float* s_w1 = (const float*)d_in[14];
  const float* s_b1 = (const float*)d_in[15];
  const float* s_g1 = (const float*)d_in[16];
  const float* s_be1 = (const float*)d_in[17];
  const float* s_w2 = (const float*)d_in[18];
  const float* s_b2 = (const float*)d_in[19];
  const float* s_g2 = (const float*)d_in[20];
  const float* s_be2 = (const float*)d_in[21];
  const float* mu_w = (const float*)d_in[22];
  const float* mu_b = (const float*)d_in[23];
  const float* sg_w = (const float*)d_in[24];
  const float* sg_b = (const float*)d_in[25];
  const float* gru_wi = (const float*)d_in[26];
  const float* gru_wh = (const float*)d_in[27];
  const float* gru_bi = (const float*)d_in[28];
  const float* gru_bh = (const float*)d_in[29];

  float* ws = (float*)d_ws;
  float* ST = ws;                                            // 256 floats
  unsigned short* Af = (unsigned short*)(ws + 256);          // 2621440 sh
  unsigned short* Bf = Af + 2621440;                         // 524288 sh
  unsigned short* W2fa = Bf + 524288;                        // 65536 sh
  unsigned short* W2fs = W2fa + 65536;                       // 65536 sh
  unsigned short* wibf = W2fs + 65536;                       // 393216 sh
  unsigned short* whbf = wibf + 393216;                      // 196608 sh
  float* PQ = (float*)(whbf + 196608);                       // 5242880 f
  float* Z2a = PQ + 5242880;                                 // 1310720 f
  float* Z2s = Z2a + 1310720;                                // 1310720 f
  float* Part = Z2s + 1310720;                               // 32768 f
  // postproc/GRU buffers alias PQ (dead after fused_layer2_half)
  unsigned short* msgbf = (unsigned short*)PQ;               // 262144 sh
  unsigned short* h0bf = msgbf + 262144;                     // 131072 sh
  float* h0 = PQ + 196608;                                   // 131072 f
  float* gi = PQ + 327680;                                   // 393216 f
  float* gh = gi + 393216;                                   // 393216 f

  hipMemsetAsync(ST, 0, 256 * sizeof(float), stream);
  prep_weights<<<1024, 256, 0, stream>>>(utt, a_w1, s_w1, a_w2, s_w2, gru_wi, gru_wh,
                                         Af, Bf, W2fa, W2fs, wibf, whbf);
  gemm_pq_swz<<<dim3(160, 4), 256, 0, stream>>>(Af, Bf, PQ);
  stats_kernel<<<dim3(512, 2), 256, 0, stream>>>(PQ, a_b1, s_b1, Part);
  reduce_bn1<<<2, 256, 0, stream>>>(Part, a_b1, s_b1, a_g1, a_be1, s_g1, s_be1, ST);
  fused_layer2_half<<<dim3(512, 2, 2), 256, 0, stream>>>(PQ, ST, a_b1, s_b1, W2fa, W2fs,
                                                         a_b2, s_b2, cl, Z2a, Z2s);
  finalize_bn2<<<1, 32, 0, stream>>>(a_g2, a_be2, s_g2, s_be2, ST);
  postproc_kernel<<<512, 256, 0, stream>>>(Z2a, Z2s, ST, a_w3, a_b3, mu_w, mu_b, sg_w, sg_b,
                                           aij_eps, sij_eps, cl, utt, msgbf, h0bf, h0);
  gemm_mfma<<<dim3(16, 3), 256, 0, stream>>>(msgbf, wibf, gi, gru_bi, 512, 768);
  gemm_mfma<<<dim3(16, 3), 256, 0, stream>>>(h0bf, whbf, gh, gru_bh, 256, 768);
  gru_final<<<512, 256, 0, stream>>>(gi, gh, h0, (float*)d_out);
}

// Round 8
// 139.100 us; speedup vs baseline: 4.6518x; 1.1944x over previous
//
#include <hip/hip_runtime.h>
#include <math.h>

// ContextEncoder: B=512, L=10, H=256, D=512.
//  prep: bf16 conversions; A/B/W2 written in MFMA *fragment order* (coalesced 1KB frag loads).
//  gemm_pq_swz: PQ[5120][1024] (bf16) = utt @ Wcat^T, swizzled operands, reg dbuf k-loop.
//  stats_kernel + reduce_bn1: BN1 closed-form from bf16 P/Q moments, per-block partials.
//  fused_layer2_half: grid (512 x 2 halves x 2 branches), bf16 P/Q -> h1 LDS -> MFMA ->
//    BN2 per-block partials (plain stores, NO global atomics) + anchor-row writes.
//  finalize_bn2: wave-parallel Part2 reduction + scale/shift.
//  postproc (bf16 msg/h0), GRU via generic gemm_mfma + elementwise.

typedef __attribute__((ext_vector_type(8))) short short8;
typedef __attribute__((ext_vector_type(4))) float f32x4;

__device__ __forceinline__ float softplusf(float x) {
  return x > 0.f ? x + log1pf(expf(-x)) : log1pf(expf(x));
}
__device__ __forceinline__ float wred64(float v) {
#pragma unroll
  for (int o = 32; o > 0; o >>= 1) v += __shfl_down(v, o);
  return v;
}
__device__ __forceinline__ unsigned short f2bf(float f) {
  unsigned int u = __float_as_uint(f);
  u += 0x7fffu + ((u >> 16) & 1u);
  return (unsigned short)(u >> 16);
}
__device__ __forceinline__ float bf2f(unsigned short u) {
  return __uint_as_float(((unsigned int)u) << 16);
}

// ---------------- prep: bf16 conversions + fragment-order swizzles ----------------
__global__ __launch_bounds__(256) void prep_weights(
    const float* __restrict__ utt,
    const float* __restrict__ a_w1, const float* __restrict__ s_w1,
    const float* __restrict__ a_w2, const float* __restrict__ s_w2,
    const float* __restrict__ gru_wi, const float* __restrict__ gru_wh,
    unsigned short* __restrict__ Af, unsigned short* __restrict__ Bf,
    unsigned short* __restrict__ W2fa, unsigned short* __restrict__ W2fs,
    unsigned short* __restrict__ wibf, unsigned short* __restrict__ whbf) {
  const int total = 2621440 + 524288 + 65536 + 65536 + 393216 + 196608;
  for (int idx = blockIdx.x * 256 + threadIdx.x; idx < total; idx += gridDim.x * 256) {
    int id = idx;
    if (id < 2621440) {  // Af: id = rb*8192 + ks*512 + lane*8 + e
      int e = id & 7, lane = (id >> 3) & 63, ks = (id >> 9) & 15, rb = id >> 13;
      int row = rb * 16 + (lane & 15);
      int k = ks * 32 + (lane >> 4) * 8 + e;
      Af[id] = f2bf(utt[row * 512 + k]); continue;
    }
    id -= 2621440;
    if (id < 524288) {  // Bf: id = cb*32768 + ks*2048 + cf*512 + lane*8 + e
      int e = id & 7, lane = (id >> 3) & 63, cf = (id >> 9) & 3, ks = (id >> 11) & 15, cb = id >> 15;
      int c = cb * 64 + cf * 16 + (lane & 15);
      int k = ks * 32 + (lane >> 4) * 8 + e;
      float v;
      if (c < 256)       v = a_w1[c * 1024 + k];
      else if (c < 512)  v = a_w1[(c - 256) * 1024 + 512 + k];
      else if (c < 768)  v = s_w1[(c - 512) * 1024 + k];
      else               v = s_w1[(c - 768) * 1024 + 512 + k];
      Bf[id] = f2bf(v); continue;
    }
    id -= 524288;
    if (id < 65536) {  // W2fa: id = cb*16384 + ks*2048 + cf*512 + lane*8 + e
      int e = id & 7, lane = (id >> 3) & 63, cf = (id >> 9) & 3, ks = (id >> 11) & 7, cb = id >> 14;
      int c = cb * 64 + cf * 16 + (lane & 15);
      int k = ks * 32 + (lane >> 4) * 8 + e;
      W2fa[id] = f2bf(a_w2[c * 256 + k]); continue;
    }
    id -= 65536;
    if (id < 65536) {  // W2fs
      int e = id & 7, lane = (id >> 3) & 63, cf = (id >> 9) & 3, ks = (id >> 11) & 7, cb = id >> 14;
      int c = cb * 64 + cf * 16 + (lane & 15);
      int k = ks * 32 + (lane >> 4) * 8 + e;
      W2fs[id] = f2bf(s_w2[c * 256 + k]); continue;
    }
    id -= 65536;
    if (id < 393216) { wibf[id] = f2bf(gru_wi[id]); continue; }
    id -= 393216;
    whbf[id] = f2bf(gru_wh[id]);
  }
}

// ---------------- PQ GEMM (bf16 out), swizzled operands, reg double-buffer ----------------
// grid (160, 4): block = 32 rows x 256 cols, K=512.
__global__ __launch_bounds__(256, 4) void gemm_pq_swz(
    const unsigned short* __restrict__ Af, const unsigned short* __restrict__ Bf,
    unsigned short* __restrict__ C) {
  int t = threadIdx.x;
  int w = t >> 6, l = t & 63, li = l & 15, lg = l >> 4;
  int rb0 = blockIdx.x * 2;
  int cb = blockIdx.y * 4 + w;
  const unsigned short* Bb = Bf + cb * (16 * 4 * 512);
  f32x4 acc[2][4] = {};
  short8 acur[2], bcur[4], anxt[2], bnxt[4];
#pragma unroll
  for (int fr = 0; fr < 2; ++fr) acur[fr] = *(const short8*)&Af[((rb0 + fr) * 16 + 0) * 512 + l * 8];
#pragma unroll
  for (int cf = 0; cf < 4; ++cf) bcur[cf] = *(const short8*)&Bb[(0 * 4 + cf) * 512 + l * 8];
  for (int ks = 0; ks < 16; ++ks) {
    if (ks < 15) {
#pragma unroll
      for (int fr = 0; fr < 2; ++fr) anxt[fr] = *(const short8*)&Af[((rb0 + fr) * 16 + ks + 1) * 512 + l * 8];
#pragma unroll
      for (int cf = 0; cf < 4; ++cf) bnxt[cf] = *(const short8*)&Bb[((ks + 1) * 4 + cf) * 512 + l * 8];
    }
#pragma unroll
    for (int fr = 0; fr < 2; ++fr)
#pragma unroll
      for (int cf = 0; cf < 4; ++cf)
        acc[fr][cf] = __builtin_amdgcn_mfma_f32_16x16x32_bf16(acur[fr], bcur[cf], acc[fr][cf], 0, 0, 0);
#pragma unroll
    for (int fr = 0; fr < 2; ++fr) acur[fr] = anxt[fr];
#pragma unroll
    for (int cf = 0; cf < 4; ++cf) bcur[cf] = bnxt[cf];
  }
  int rowBase = blockIdx.x * 32, colBase = cb * 64;
#pragma unroll
  for (int fr = 0; fr < 2; ++fr)
#pragma unroll
    for (int reg = 0; reg < 4; ++reg) {
      int r = rowBase + fr * 16 + lg * 4 + reg;
      unsigned short* crow = C + r * 1024 + colBase + li;
#pragma unroll
      for (int cf = 0; cf < 4; ++cf) crow[cf * 16] = f2bf(acc[fr][cf][reg]);
    }
}

// ---------------- BN1 stats: one block per (dialog, branch), per-block partials ----------------
__global__ __launch_bounds__(256) void stats_kernel(
    const unsigned short* __restrict__ PQ, const float* __restrict__ a_b1,
    const float* __restrict__ s_b1, float* __restrict__ Part) {
  __shared__ float lbins[4][32];
  int b = blockIdx.x, br = blockIdx.y, t = threadIdx.x;
  int w = t >> 6, l = t & 63;
  const unsigned short* base = PQ + b * 10240 + (br ? 512 : 0);
  const float* b1 = br ? s_b1 : a_b1;
  float P[10], Q[10];
#pragma unroll
  for (int j = 0; j < 10; ++j) Q[j] = bf2f(base[j * 1024 + 256 + t]);
#pragma unroll
  for (int i = 0; i < 10; ++i) P[i] = bf2f(base[i * 1024 + t]);
  float sq = 0.f, sq2 = 0.f;
#pragma unroll
  for (int j = 0; j < 10; ++j) { sq += Q[j]; sq2 += Q[j] * Q[j]; }
  float qbar = sq * 0.1f;
  float bb1 = b1[t];
  float r;
  r = wred64(sq);  if (l == 0) lbins[w][0] = r;
  r = wred64(sq2); if (l == 0) lbins[w][1] = r;
#pragma unroll
  for (int i = 0; i < 10; ++i) {
    float a = P[i] + bb1;
    r = wred64(P[i]);     if (l == 0) lbins[w][2 + i * 3] = r;
    r = wred64(a * a);    if (l == 0) lbins[w][3 + i * 3] = r;
    r = wred64(a * qbar); if (l == 0) lbins[w][4 + i * 3] = r;
  }
  __syncthreads();
  if (t < 32) Part[(b * 2 + br) * 32 + t] = lbins[0][t] + lbins[1][t] + lbins[2][t] + lbins[3][t];
}

// ---------------- reduce partials + BN1 closed-form finalize (grid = 2 branches) ----------------
__global__ void reduce_bn1(const float* __restrict__ Part,
                           const float* __restrict__ a_b1, const float* __restrict__ s_b1,
                           const float* __restrict__ a_g1, const float* __restrict__ a_be1,
                           const float* __restrict__ s_g1, const float* __restrict__ s_be1,
                           float* __restrict__ ST) {
  __shared__ float tmp[256];
  __shared__ float mom[32];
  int br = blockIdx.x, t = threadIdx.x;
  int v = t & 31, c = t >> 5;
  float s = 0.f;
  for (int b = c * 64; b < c * 64 + 64; ++b) s += Part[(b * 2 + br) * 32 + v];
  tmp[t] = s;
  __syncthreads();
  if (t < 32) {
    float m = 0.f;
#pragma unroll
    for (int k = 0; k < 8; ++k) m += tmp[k * 32 + t];
    mom[t] = m;
  }
  __syncthreads();
  if (t < 10) {
    int i = t;
    const float* b1 = br ? s_b1 : a_b1;
    float bsum = 0.f;
    for (int h = 0; h < 256; ++h) bsum += b1[h];
    float meanb1 = bsum * (1.f / 256.f);
    const float invBH = 1.f / (512.f * 256.f);
    const float invBLH = 1.f / (512.f * 10.f * 256.f);
    float SP = mom[2 + i * 3], SA2 = mom[3 + i * 3], SPQ = mom[4 + i * 3];
    float SQ = mom[0], SQ2 = mom[1];
    float mean = SP * invBH + meanb1 + SQ * invBLH;
    float Ez2 = SA2 * invBH + 2.f * SPQ * invBH + SQ2 * invBLH;
    float var = Ez2 - mean * mean;
    float g = br ? s_g1[i] : a_g1[i];
    float be = br ? s_be1[i] : a_be1[i];
    float sc = g / sqrtf(var + 1e-5f);
    ST[64 + br * 20 + i] = sc;
    ST[64 + br * 20 + 10 + i] = be - mean * sc;
  }
}

// ---------------- fused layer2: block = (dialog, i-half, branch); NO global atomics ----------------
// Part2 layout: sum at [(br*10+i)*512 + b], sumsq at [10240 + (br*10+i)*512 + b].
__global__ __launch_bounds__(256, 4) void fused_layer2_half(
    const unsigned short* __restrict__ PQ, const float* __restrict__ ST,
    const float* __restrict__ a_b1, const float* __restrict__ s_b1,
    const unsigned short* __restrict__ W2fa, const unsigned short* __restrict__ W2fs,
    const float* __restrict__ a_b2, const float* __restrict__ s_b2,
    const int* __restrict__ cl, float* __restrict__ Z2a, float* __restrict__ Z2s,
    float* __restrict__ Part2) {
  __shared__ __align__(16) unsigned short Atile[64][264];
  __shared__ float bins[10];
  int b = blockIdx.x, half = blockIdx.y, br = blockIdx.z;
  int i0 = half * 5;
  int p_off = br ? 512 : 0;
  const float* b1 = br ? s_b1 : a_b1;
  const unsigned short* W2f = br ? W2fs : W2fa;
  const float* b2 = br ? s_b2 : a_b2;
  float* Z2out = br ? Z2s : Z2a;
  int sc_off = br ? 84 : 64;
  int t = threadIdx.x;
  int anc = cl[b] - 1;
  if (t < 10) bins[t] = 0.f;
  for (int idx = t; idx < 14 * 264; idx += 256) (&Atile[50][0])[idx] = 0;
  // ---- h1 phase: thread t = column c; bf16 P/Q loads ----
  {
    int c = t;
    float b1c = b1[c];
    float P[5], Q[10];
#pragma unroll
    for (int j = 0; j < 10; ++j) Q[j] = bf2f(PQ[(b * 10 + j) * 1024 + p_off + 256 + c]);
#pragma unroll
    for (int il = 0; il < 5; ++il) P[il] = bf2f(PQ[(b * 10 + i0 + il) * 1024 + p_off + c]);
#pragma unroll
    for (int il = 0; il < 5; ++il) {
      float sc = ST[sc_off + i0 + il], sh = ST[sc_off + 10 + i0 + il];
      float base = (P[il] + b1c) * sc + sh;
#pragma unroll
      for (int j = 0; j < 10; ++j) {
        float z = base + Q[j] * sc;
        float h;
        if (br) {
          float ex = __expf(2.f * z);
          h = (ex - 1.f) / (ex + 1.f);
        } else {
          h = fmaxf(z, 0.f);
        }
        Atile[il * 10 + j][c] = f2bf(h);
      }
    }
  }
  __syncthreads();
  // ---- MFMA: wave w owns 64 cols, 64 rows (50 valid); W2 frags coalesced + prefetched ----
  int w = t >> 6, l = t & 63, li = l & 15, lg = l >> 4;
  int colBase = w * 64;
  const unsigned short* Wb = W2f + w * (8 * 4 * 512);
  f32x4 acc[4][4] = {};
  short8 bcur[4], bnxt[4];
#pragma unroll
  for (int cf = 0; cf < 4; ++cf) bcur[cf] = *(const short8*)&Wb[(0 * 4 + cf) * 512 + l * 8];
  for (int ks = 0; ks < 8; ++ks) {
    if (ks < 7) {
#pragma unroll
      for (int cf = 0; cf < 4; ++cf) bnxt[cf] = *(const short8*)&Wb[((ks + 1) * 4 + cf) * 512 + l * 8];
    }
    int ka = ks * 32 + lg * 8;
#pragma unroll
    for (int fr = 0; fr < 4; ++fr) {
      short8 afr = *(const short8*)&Atile[fr * 16 + li][ka];
#pragma unroll
      for (int cf = 0; cf < 4; ++cf)
        acc[fr][cf] = __builtin_amdgcn_mfma_f32_16x16x32_bf16(afr, bcur[cf], acc[fr][cf], 0, 0, 0);
    }
#pragma unroll
    for (int cf = 0; cf < 4; ++cf) bcur[cf] = bnxt[cf];
  }
  // ---- epilogue: bias, anchor-row writes, BN2 bins (LDS only) ----
  float b2v[4];
#pragma unroll
  for (int cf = 0; cf < 4; ++cf) b2v[cf] = b2[colBase + cf * 16 + li];
#pragma unroll
  for (int fr = 0; fr < 4; ++fr) {
#pragma unroll
    for (int reg = 0; reg < 4; ++reg) {
      int row = fr * 16 + lg * 4 + reg;
      bool valid = row < 50;
      int il = row / 10, jj = row - il * 10;
      float z0 = acc[fr][0][reg] + b2v[0];
      float z1 = acc[fr][1][reg] + b2v[1];
      float z2 = acc[fr][2][reg] + b2v[2];
      float z3 = acc[fr][3][reg] + b2v[3];
      if (valid && (i0 + il) == anc) {
        float* dst = Z2out + (b * 10 + jj) * 256 + colBase + li;
        dst[0] = z0; dst[16] = z1; dst[32] = z2; dst[48] = z3;
      }
      float s = valid ? (z0 + z1 + z2 + z3) : 0.f;
      float q = valid ? (z0 * z0 + z1 * z1 + z2 * z2 + z3 * z3) : 0.f;
#pragma unroll
      for (int o = 1; o < 16; o <<= 1) {
        s += __shfl_xor(s, o);
        q += __shfl_xor(q, o);
      }
      if (li == 0 && valid) {
        atomicAdd(&bins[il], s);
        atomicAdd(&bins[5 + il], q);
      }
    }
  }
  __syncthreads();
  if (t < 5) {
    Part2[(br * 10 + i0 + t) * 512 + b] = bins[t];
    Part2[10240 + (br * 10 + i0 + t) * 512 + b] = bins[5 + t];
  }
}

// ---------------- BN2 finalize: wave-parallel Part2 reduction ----------------
__global__ __launch_bounds__(256) void finalize_bn2(
    const float* __restrict__ Part2,
    const float* __restrict__ a_g2, const float* __restrict__ a_be2,
    const float* __restrict__ s_g2, const float* __restrict__ s_be2,
    float* __restrict__ ST) {
  int t = threadIdx.x;
  int w = t >> 6, l = t & 63;
  // 4 waves x 5 pairs = 20 (br,i) pairs
#pragma unroll
  for (int pp = 0; pp < 5; ++pp) {
    int p = w * 5 + pp;  // p = br*10 + i
    float s = 0.f, q = 0.f;
#pragma unroll
    for (int k = 0; k < 8; ++k) {
      s += Part2[p * 512 + l + k * 64];
      q += Part2[10240 + p * 512 + l + k * 64];
    }
    s = wred64(s);
    q = wred64(q);
    if (l == 0) {
      int br = p / 10, i = p - br * 10;
      const float invN = 1.f / (512.f * 10.f * 256.f);
      float m = s * invN;
      float v = q * invN - m * m;
      float g = br ? s_g2[i] : a_g2[i];
      float be = br ? s_be2[i] : a_be2[i];
      float sc = g / sqrtf(v + 1e-5f);
      ST[144 + br * 20 + i] = sc;
      ST[144 + br * 20 + 10 + i] = be - m * sc;
    }
  }
}

// ---------------- generic MFMA GEMM (32-row tiles), for GRU ----------------
__global__ __launch_bounds__(256) void gemm_mfma(
    const unsigned short* __restrict__ A, const unsigned short* __restrict__ Bw,
    float* __restrict__ C, const float* __restrict__ bias, int K, int N) {
  int t = threadIdx.x;
  int w = t >> 6, l = t & 63, li = l & 15, lg = l >> 4;
  int rowBase = blockIdx.x * 32;
  int colBase = blockIdx.y * 256 + w * 64;
  f32x4 acc[2][4] = {};
  const unsigned short* Arow[2];
  const unsigned short* Brow[4];
#pragma unroll
  for (int fr = 0; fr < 2; ++fr) Arow[fr] = A + (rowBase + fr * 16 + li) * K;
#pragma unroll
  for (int cf = 0; cf < 4; ++cf) Brow[cf] = Bw + (colBase + cf * 16 + li) * K;
  for (int ks = 0; ks < K / 32; ++ks) {
    int ka = ks * 32 + lg * 8;
    short8 afr[2], bfr[4];
#pragma unroll
    for (int fr = 0; fr < 2; ++fr) afr[fr] = *(const short8*)&Arow[fr][ka];
#pragma unroll
    for (int cf = 0; cf < 4; ++cf) bfr[cf] = *(const short8*)&Brow[cf][ka];
#pragma unroll
    for (int fr = 0; fr < 2; ++fr)
#pragma unroll
      for (int cf = 0; cf < 4; ++cf)
        acc[fr][cf] = __builtin_amdgcn_mfma_f32_16x16x32_bf16(afr[fr], bfr[cf], acc[fr][cf], 0, 0, 0);
  }
  float b2v[4] = {0.f, 0.f, 0.f, 0.f};
  if (bias) {
#pragma unroll
    for (int cf = 0; cf < 4; ++cf) b2v[cf] = bias[colBase + cf * 16 + li];
  }
#pragma unroll
  for (int fr = 0; fr < 2; ++fr)
#pragma unroll
    for (int reg = 0; reg < 4; ++reg) {
      int r = rowBase + fr * 16 + lg * 4 + reg;
      float* crow = C + r * N + colBase + li;
#pragma unroll
      for (int cf = 0; cf < 4; ++cf) crow[cf * 16] = acc[fr][cf][reg] + b2v[cf];
    }
}

// ---------------- postproc ----------------
__global__ __launch_bounds__(256) void postproc_kernel(
    const float* __restrict__ Z2a, const float* __restrict__ Z2s, const float* __restrict__ ST,
    const float* __restrict__ a_w3, const float* __restrict__ a_b3,
    const float* __restrict__ mu_w, const float* __restrict__ mu_b,
    const float* __restrict__ sg_w, const float* __restrict__ sg_b,
    const float* __restrict__ aij_eps, const float* __restrict__ sij_eps,
    const int* __restrict__ cl, const float* __restrict__ utt,
    unsigned short* __restrict__ msgbf, unsigned short* __restrict__ h0bf,
    float* __restrict__ h0out) {
  int b = blockIdx.x, t = threadIdx.x;
  int a = cl[b] - 1;
  float sc2a = ST[144 + a], sh2a = ST[154 + a];
  float sc2s = ST[164 + a], sh2s = ST[174 + a];
  float w3 = a_w3[t], mw = mu_w[t], sw = sg_w[t];
  __shared__ float red[30];
  if (t < 30) red[t] = 0.f;
  __syncthreads();
#pragma unroll
  for (int j = 0; j < 10; ++j) {
    float za = Z2a[(b * 10 + j) * 256 + t];
    float va = fmaxf(za * sc2a + sh2a, 0.f);
    float zs = Z2s[(b * 10 + j) * 256 + t];
    float vs = tanhf(zs * sc2s + sh2s);
    float pa = wred64(va * w3);
    float pm = wred64(vs * mw);
    float ps = wred64(vs * sw);
    if ((t & 63) == 0) {
      atomicAdd(&red[j], pa);
      atomicAdd(&red[10 + j], pm);
      atomicAdd(&red[20 + j], ps);
    }
  }
  __syncthreads();
  __shared__ float pw[10];
  __shared__ float wijs[16];
  if (t < 10) {
    int j = t;
    float amij = red[j] + a_b3[0];
    float amu = softplusf(amij) + 0.01f;
    float astd = sqrtf(softplusf((1.f - amu) * amu) + 0.01f);
    float ae = aij_eps[b * 100 + a * 10 + j];
    float aij = softplusf(ae * astd + amu) + 0.01f;
    float smu = red[10 + j] + mu_b[0];
    float ssg = red[20 + j] + sg_b[0];
    float se = sij_eps[b * 100 + a * 10 + j];
    float sij = se * sqrtf(aij * ssg * ssg) + aij * smu;
    wijs[j] = aij * sij;
  }
  __syncthreads();
  if (t == 0) {
    float mx = -1e30f;
    for (int j = 0; j < a; ++j) mx = fmaxf(mx, wijs[j]);
    float e[10];
    float den = 0.f;
    for (int j = 0; j < a; ++j) { e[j] = expf(wijs[j] - mx); den += e[j]; }
    for (int j = 0; j < 10; ++j) pw[j] = (j < a) ? e[j] / den : 0.f;
  }
  __syncthreads();
#pragma unroll
  for (int dd = 0; dd < 2; ++dd) {
    int d = t + dd * 256;
    float mv = 0.f;
#pragma unroll
    for (int j = 0; j < 10; ++j) mv += pw[j] * utt[(b * 10 + j) * 512 + d];
    msgbf[b * 512 + d] = f2bf(mv);
  }
  float u1 = utt[(b * 10 + a) * 512 + t];
  float u2 = utt[(b * 10 + a) * 512 + 256 + t];
  float h0v = u1 + u2;
  h0out[b * 256 + t] = h0v;
  h0bf[b * 256 + t] = f2bf(h0v);
}

// ---------------- GRU elementwise ----------------
__global__ __launch_bounds__(256) void gru_final(const float* __restrict__ gi,
                                                 const float* __restrict__ gh,
                                                 const float* __restrict__ h0,
                                                 float* __restrict__ out) {
  int idx = blockIdx.x * 256 + threadIdx.x;
  int b = idx >> 8, h = idx & 255;
  float ir = gi[b * 768 + h], iz = gi[b * 768 + 256 + h], inn = gi[b * 768 + 512 + h];
  float hr = gh[b * 768 + h], hz = gh[b * 768 + 256 + h], hn = gh[b * 768 + 512 + h];
  float r = 1.f / (1.f + expf(-(ir + hr)));
  float z = 1.f / (1.f + expf(-(iz + hz)));
  float n = tanhf(inn + r * hn);
  out[idx] = (1.f - z) * n + z * h0[b * 256 + h];
}

extern "C" void kernel_launch(void* const* d_in, const int* in_sizes, int n_in,
                              void* d_out, int out_size, void* d_ws, size_t ws_size,
                              hipStream_t stream) {
  const float* utt = (const float*)d_in[0];
  const float* aij_eps = (const float*)d_in[1];
  const float* sij_eps = (const float*)d_in[2];
  const int* cl = (const int*)d_in[3];
  const float* a_w1 = (const float*)d_in[4];
  const float* a_b1 = (const float*)d_in[5];
  const float* a_g1 = (const float*)d_in[6];
  const float* a_be1 = (const float*)d_in[7];
  const float* a_w2 = (const float*)d_in[8];
  const float* a_b2 = (const float*)d_in[9];
  const float* a_g2 = (const float*)d_in[10];
  const float* a_be2 = (const float*)d_in[11];
  const float* a_w3 = (const float*)d_in[12];
  const float* a_b3 = (const float*)d_in[13];
  const float* s_w1 = (const float*)d_in[14];
  const float* s_b1 = (const float*)d_in[15];
  const float* s_g1 = (const float*)d_in[16];
  const float* s_be1 = (const float*)d_in[17];
  const float* s_w2 = (const float*)d_in[18];
  const float* s_b2 = (const float*)d_in[19];
  const float* s_g2 = (const float*)d_in[20];
  const float* s_be2 = (const float*)d_in[21];
  const float* mu_w = (const float*)d_in[22];
  const float* mu_b = (const float*)d_in[23];
  const float* sg_w = (const float*)d_in[24];
  const float* sg_b = (const float*)d_in[25];
  const float* gru_wi = (const float*)d_in[26];
  const float* gru_wh = (const float*)d_in[27];
  const float* gru_bi = (const float*)d_in[28];
  const float* gru_bh = (const float*)d_in[29];

  float* ws = (float*)d_ws;
  float* ST = ws;                                            // 256 floats
  unsigned short* Af = (unsigned short*)(ws + 256);          // 2621440 sh
  unsigned short* Bf = Af + 2621440;                         // 524288 sh
  unsigned short* W2fa = Bf + 524288;                        // 65536 sh
  unsigned short* W2fs = W2fa + 65536;                       // 65536 sh
  unsigned short* wibf = W2fs + 65536;                       // 393216 sh
  unsigned short* whbf = wibf + 393216;                      // 196608 sh
  float* PQf = (float*)(whbf + 196608);                      // region: 5242880 f (PQ bf16 uses half)
  unsigned short* PQ = (unsigned short*)PQf;                 // 5242880 sh used
  float* Z2a = PQf + 5242880;                                // 1310720 f
  float* Z2s = Z2a + 1310720;                                // 1310720 f
  float* Part = Z2s + 1310720;                               // 32768 f
  float* Part2 = Part + 32768;                               // 20480 f
  // postproc/GRU buffers alias the tail of the PQ region (PQ bf16 occupies first half only)
  float* tailf = PQf + 2621440;                              // 2621440 f free
  unsigned short* msgbf = (unsigned short*)tailf;            // 262144 sh
  unsigned short* h0bf = msgbf + 262144;                     // 131072 sh
  float* h0 = tailf + 196608;                                // 131072 f
  float* gi = tailf + 327680;                                // 393216 f
  float* gh = gi + 393216;                                   // 393216 f

  hipMemsetAsync(ST, 0, 256 * sizeof(float), stream);
  prep_weights<<<1024, 256, 0, stream>>>(utt, a_w1, s_w1, a_w2, s_w2, gru_wi, gru_wh,
                                         Af, Bf, W2fa, W2fs, wibf, whbf);
  gemm_pq_swz<<<dim3(160, 4), 256, 0, stream>>>(Af, Bf, PQ);
  stats_kernel<<<dim3(512, 2), 256, 0, stream>>>(PQ, a_b1, s_b1, Part);
  reduce_bn1<<<2, 256, 0, stream>>>(Part, a_b1, s_b1, a_g1, a_be1, s_g1, s_be1, ST);
  fused_layer2_half<<<dim3(512, 2, 2), 256, 0, stream>>>(PQ, ST, a_b1, s_b1, W2fa, W2fs,
                                                         a_b2, s_b2, cl, Z2a, Z2s, Part2);
  finalize_bn2<<<1, 256, 0, stream>>>(Part2, a_g2, a_be2, s_g2, s_be2, ST);
  postproc_kernel<<<512, 256, 0, stream>>>(Z2a, Z2s, ST, a_w3, a_b3, mu_w, mu_b, sg_w, sg_b,
                                           aij_eps, sij_eps, cl, utt, msgbf, h0bf, h0);
  gemm_mfma<<<dim3(16, 3), 256, 0, stream>>>(msgbf, wibf, gi, gru_bi, 512, 768);
  gemm_mfma<<<dim3(16, 3), 256, 0, stream>>>(h0bf, whbf, gh, gru_bh, 256, 768);
  gru_final<<<512, 256, 0, stream>>>(gi, gh, h0, (float*)d_out);
}

// Round 9
// 133.968 us; speedup vs baseline: 4.8300x; 1.0383x over previous
//
#include <hip/hip_runtime.h>
#include <math.h>

// ContextEncoder: B=512, L=10, H=256, D=512.
//  prep: bf16 conversions; A/B/W2 written in MFMA *fragment order* (coalesced 1KB frag loads).
//  gemm_pq_swz: PQ[5120][1024] (bf16) = utt @ Wcat^T, swizzled operands, reg dbuf k-loop.
//  stats_kernel + reduce_bn1: BN1 closed-form from bf16 P/Q moments, per-block partials.
//  fused_layer2_half: grid (512 x 2 halves x 2 branches), bf16 P/Q -> h1 LDS -> MFMA ->
//    BN2 per-block partials (plain stores, NO global atomics) + anchor-row writes.
//  finalize_bn2: wave-parallel Part2 reduction + scale/shift.
//  postproc (bf16 msg/h0), GRU via generic gemm_mfma + elementwise.
//  NOTE: no memset needed — every ST/Part/Part2 slot read is written first in-launch.

typedef __attribute__((ext_vector_type(8))) short short8;
typedef __attribute__((ext_vector_type(4))) float f32x4;

__device__ __forceinline__ float softplusf(float x) {
  return x > 0.f ? x + log1pf(expf(-x)) : log1pf(expf(x));
}
__device__ __forceinline__ float wred64(float v) {
#pragma unroll
  for (int o = 32; o > 0; o >>= 1) v += __shfl_down(v, o);
  return v;
}
__device__ __forceinline__ unsigned short f2bf(float f) {
  unsigned int u = __float_as_uint(f);
  u += 0x7fffu + ((u >> 16) & 1u);
  return (unsigned short)(u >> 16);
}
__device__ __forceinline__ float bf2f(unsigned short u) {
  return __uint_as_float(((unsigned int)u) << 16);
}

// ---------------- prep: bf16 conversions + fragment-order swizzles ----------------
__global__ __launch_bounds__(256) void prep_weights(
    const float* __restrict__ utt,
    const float* __restrict__ a_w1, const float* __restrict__ s_w1,
    const float* __restrict__ a_w2, const float* __restrict__ s_w2,
    const float* __restrict__ gru_wi, const float* __restrict__ gru_wh,
    unsigned short* __restrict__ Af, unsigned short* __restrict__ Bf,
    unsigned short* __restrict__ W2fa, unsigned short* __restrict__ W2fs,
    unsigned short* __restrict__ wibf, unsigned short* __restrict__ whbf) {
  const int total = 2621440 + 524288 + 65536 + 65536 + 393216 + 196608;
  for (int idx = blockIdx.x * 256 + threadIdx.x; idx < total; idx += gridDim.x * 256) {
    int id = idx;
    if (id < 2621440) {  // Af: id = rb*8192 + ks*512 + lane*8 + e
      int e = id & 7, lane = (id >> 3) & 63, ks = (id >> 9) & 15, rb = id >> 13;
      int row = rb * 16 + (lane & 15);
      int k = ks * 32 + (lane >> 4) * 8 + e;
      Af[id] = f2bf(utt[row * 512 + k]); continue;
    }
    id -= 2621440;
    if (id < 524288) {  // Bf: id = cb*32768 + ks*2048 + cf*512 + lane*8 + e
      int e = id & 7, lane = (id >> 3) & 63, cf = (id >> 9) & 3, ks = (id >> 11) & 15, cb = id >> 15;
      int c = cb * 64 + cf * 16 + (lane & 15);
      int k = ks * 32 + (lane >> 4) * 8 + e;
      float v;
      if (c < 256)       v = a_w1[c * 1024 + k];
      else if (c < 512)  v = a_w1[(c - 256) * 1024 + 512 + k];
      else if (c < 768)  v = s_w1[(c - 512) * 1024 + k];
      else               v = s_w1[(c - 768) * 1024 + 512 + k];
      Bf[id] = f2bf(v); continue;
    }
    id -= 524288;
    if (id < 65536) {  // W2fa: id = cb*16384 + ks*2048 + cf*512 + lane*8 + e
      int e = id & 7, lane = (id >> 3) & 63, cf = (id >> 9) & 3, ks = (id >> 11) & 7, cb = id >> 14;
      int c = cb * 64 + cf * 16 + (lane & 15);
      int k = ks * 32 + (lane >> 4) * 8 + e;
      W2fa[id] = f2bf(a_w2[c * 256 + k]); continue;
    }
    id -= 65536;
    if (id < 65536) {  // W2fs
      int e = id & 7, lane = (id >> 3) & 63, cf = (id >> 9) & 3, ks = (id >> 11) & 7, cb = id >> 14;
      int c = cb * 64 + cf * 16 + (lane & 15);
      int k = ks * 32 + (lane >> 4) * 8 + e;
      W2fs[id] = f2bf(s_w2[c * 256 + k]); continue;
    }
    id -= 65536;
    if (id < 393216) { wibf[id] = f2bf(gru_wi[id]); continue; }
    id -= 393216;
    whbf[id] = f2bf(gru_wh[id]);
  }
}

// ---------------- PQ GEMM (bf16 out), swizzled operands, reg double-buffer ----------------
// grid (160, 4): block = 32 rows x 256 cols, K=512.
__global__ __launch_bounds__(256, 4) void gemm_pq_swz(
    const unsigned short* __restrict__ Af, const unsigned short* __restrict__ Bf,
    unsigned short* __restrict__ C) {
  int t = threadIdx.x;
  int w = t >> 6, l = t & 63, li = l & 15, lg = l >> 4;
  int rb0 = blockIdx.x * 2;
  int cb = blockIdx.y * 4 + w;
  const unsigned short* Bb = Bf + cb * (16 * 4 * 512);
  f32x4 acc[2][4] = {};
  short8 acur[2], bcur[4], anxt[2], bnxt[4];
#pragma unroll
  for (int fr = 0; fr < 2; ++fr) acur[fr] = *(const short8*)&Af[((rb0 + fr) * 16 + 0) * 512 + l * 8];
#pragma unroll
  for (int cf = 0; cf < 4; ++cf) bcur[cf] = *(const short8*)&Bb[(0 * 4 + cf) * 512 + l * 8];
  for (int ks = 0; ks < 16; ++ks) {
    if (ks < 15) {
#pragma unroll
      for (int fr = 0; fr < 2; ++fr) anxt[fr] = *(const short8*)&Af[((rb0 + fr) * 16 + ks + 1) * 512 + l * 8];
#pragma unroll
      for (int cf = 0; cf < 4; ++cf) bnxt[cf] = *(const short8*)&Bb[((ks + 1) * 4 + cf) * 512 + l * 8];
    }
#pragma unroll
    for (int fr = 0; fr < 2; ++fr)
#pragma unroll
      for (int cf = 0; cf < 4; ++cf)
        acc[fr][cf] = __builtin_amdgcn_mfma_f32_16x16x32_bf16(acur[fr], bcur[cf], acc[fr][cf], 0, 0, 0);
#pragma unroll
    for (int fr = 0; fr < 2; ++fr) acur[fr] = anxt[fr];
#pragma unroll
    for (int cf = 0; cf < 4; ++cf) bcur[cf] = bnxt[cf];
  }
  int rowBase = blockIdx.x * 32, colBase = cb * 64;
#pragma unroll
  for (int fr = 0; fr < 2; ++fr)
#pragma unroll
    for (int reg = 0; reg < 4; ++reg) {
      int r = rowBase + fr * 16 + lg * 4 + reg;
      unsigned short* crow = C + r * 1024 + colBase + li;
#pragma unroll
      for (int cf = 0; cf < 4; ++cf) crow[cf * 16] = f2bf(acc[fr][cf][reg]);
    }
}

// ---------------- BN1 stats: one block per (dialog, branch), per-block partials ----------------
__global__ __launch_bounds__(256) void stats_kernel(
    const unsigned short* __restrict__ PQ, const float* __restrict__ a_b1,
    const float* __restrict__ s_b1, float* __restrict__ Part) {
  __shared__ float lbins[4][32];
  int b = blockIdx.x, br = blockIdx.y, t = threadIdx.x;
  int w = t >> 6, l = t & 63;
  const unsigned short* base = PQ + b * 10240 + (br ? 512 : 0);
  const float* b1 = br ? s_b1 : a_b1;
  float P[10], Q[10];
#pragma unroll
  for (int j = 0; j < 10; ++j) Q[j] = bf2f(base[j * 1024 + 256 + t]);
#pragma unroll
  for (int i = 0; i < 10; ++i) P[i] = bf2f(base[i * 1024 + t]);
  float sq = 0.f, sq2 = 0.f;
#pragma unroll
  for (int j = 0; j < 10; ++j) { sq += Q[j]; sq2 += Q[j] * Q[j]; }
  float qbar = sq * 0.1f;
  float bb1 = b1[t];
  float r;
  r = wred64(sq);  if (l == 0) lbins[w][0] = r;
  r = wred64(sq2); if (l == 0) lbins[w][1] = r;
#pragma unroll
  for (int i = 0; i < 10; ++i) {
    float a = P[i] + bb1;
    r = wred64(P[i]);     if (l == 0) lbins[w][2 + i * 3] = r;
    r = wred64(a * a);    if (l == 0) lbins[w][3 + i * 3] = r;
    r = wred64(a * qbar); if (l == 0) lbins[w][4 + i * 3] = r;
  }
  __syncthreads();
  if (t < 32) Part[(b * 2 + br) * 32 + t] = lbins[0][t] + lbins[1][t] + lbins[2][t] + lbins[3][t];
}

// ---------------- reduce partials + BN1 closed-form finalize (grid = 2 branches) ----------------
__global__ void reduce_bn1(const float* __restrict__ Part,
                           const float* __restrict__ a_b1, const float* __restrict__ s_b1,
                           const float* __restrict__ a_g1, const float* __restrict__ a_be1,
                           const float* __restrict__ s_g1, const float* __restrict__ s_be1,
                           float* __restrict__ ST) {
  __shared__ float tmp[256];
  __shared__ float mom[32];
  int br = blockIdx.x, t = threadIdx.x;
  int v = t & 31, c = t >> 5;
  float s = 0.f;
  for (int b = c * 64; b < c * 64 + 64; ++b) s += Part[(b * 2 + br) * 32 + v];
  tmp[t] = s;
  __syncthreads();
  if (t < 32) {
    float m = 0.f;
#pragma unroll
    for (int k = 0; k < 8; ++k) m += tmp[k * 32 + t];
    mom[t] = m;
  }
  __syncthreads();
  if (t < 10) {
    int i = t;
    const float* b1 = br ? s_b1 : a_b1;
    float bsum = 0.f;
    for (int h = 0; h < 256; ++h) bsum += b1[h];
    float meanb1 = bsum * (1.f / 256.f);
    const float invBH = 1.f / (512.f * 256.f);
    const float invBLH = 1.f / (512.f * 10.f * 256.f);
    float SP = mom[2 + i * 3], SA2 = mom[3 + i * 3], SPQ = mom[4 + i * 3];
    float SQ = mom[0], SQ2 = mom[1];
    float mean = SP * invBH + meanb1 + SQ * invBLH;
    float Ez2 = SA2 * invBH + 2.f * SPQ * invBH + SQ2 * invBLH;
    float var = Ez2 - mean * mean;
    float g = br ? s_g1[i] : a_g1[i];
    float be = br ? s_be1[i] : a_be1[i];
    float sc = g / sqrtf(var + 1e-5f);
    ST[64 + br * 20 + i] = sc;
    ST[64 + br * 20 + 10 + i] = be - mean * sc;
  }
}

// ---------------- fused layer2: block = (dialog, i-half, branch); NO global atomics ----------------
// Part2 layout: sum at [(br*10+i)*512 + b], sumsq at [10240 + (br*10+i)*512 + b].
__global__ __launch_bounds__(256, 4) void fused_layer2_half(
    const unsigned short* __restrict__ PQ, const float* __restrict__ ST,
    const float* __restrict__ a_b1, const float* __restrict__ s_b1,
    const unsigned short* __restrict__ W2fa, const unsigned short* __restrict__ W2fs,
    const float* __restrict__ a_b2, const float* __restrict__ s_b2,
    const int* __restrict__ cl, float* __restrict__ Z2a, float* __restrict__ Z2s,
    float* __restrict__ Part2) {
  __shared__ __align__(16) unsigned short Atile[64][264];
  __shared__ float bins[10];
  int b = blockIdx.x, half = blockIdx.y, br = blockIdx.z;
  int i0 = half * 5;
  int p_off = br ? 512 : 0;
  const float* b1 = br ? s_b1 : a_b1;
  const unsigned short* W2f = br ? W2fs : W2fa;
  const float* b2 = br ? s_b2 : a_b2;
  float* Z2out = br ? Z2s : Z2a;
  int sc_off = br ? 84 : 64;
  int t = threadIdx.x;
  int anc = cl[b] - 1;
  if (t < 10) bins[t] = 0.f;
  for (int idx = t; idx < 14 * 264; idx += 256) (&Atile[50][0])[idx] = 0;
  // ---- h1 phase: thread t = column c; bf16 P/Q loads ----
  {
    int c = t;
    float b1c = b1[c];
    float P[5], Q[10];
#pragma unroll
    for (int j = 0; j < 10; ++j) Q[j] = bf2f(PQ[(b * 10 + j) * 1024 + p_off + 256 + c]);
#pragma unroll
    for (int il = 0; il < 5; ++il) P[il] = bf2f(PQ[(b * 10 + i0 + il) * 1024 + p_off + c]);
#pragma unroll
    for (int il = 0; il < 5; ++il) {
      float sc = ST[sc_off + i0 + il], sh = ST[sc_off + 10 + i0 + il];
      float base = (P[il] + b1c) * sc + sh;
#pragma unroll
      for (int j = 0; j < 10; ++j) {
        float z = base + Q[j] * sc;
        float h;
        if (br) {
          float ex = __expf(2.f * z);
          h = (ex - 1.f) / (ex + 1.f);
        } else {
          h = fmaxf(z, 0.f);
        }
        Atile[il * 10 + j][c] = f2bf(h);
      }
    }
  }
  __syncthreads();
  // ---- MFMA: wave w owns 64 cols, 64 rows (50 valid); W2 frags coalesced + prefetched ----
  int w = t >> 6, l = t & 63, li = l & 15, lg = l >> 4;
  int colBase = w * 64;
  const unsigned short* Wb = W2f + w * (8 * 4 * 512);
  f32x4 acc[4][4] = {};
  short8 bcur[4], bnxt[4];
#pragma unroll
  for (int cf = 0; cf < 4; ++cf) bcur[cf] = *(const short8*)&Wb[(0 * 4 + cf) * 512 + l * 8];
  for (int ks = 0; ks < 8; ++ks) {
    if (ks < 7) {
#pragma unroll
      for (int cf = 0; cf < 4; ++cf) bnxt[cf] = *(const short8*)&Wb[((ks + 1) * 4 + cf) * 512 + l * 8];
    }
    int ka = ks * 32 + lg * 8;
#pragma unroll
    for (int fr = 0; fr < 4; ++fr) {
      short8 afr = *(const short8*)&Atile[fr * 16 + li][ka];
#pragma unroll
      for (int cf = 0; cf < 4; ++cf)
        acc[fr][cf] = __builtin_amdgcn_mfma_f32_16x16x32_bf16(afr, bcur[cf], acc[fr][cf], 0, 0, 0);
    }
#pragma unroll
    for (int cf = 0; cf < 4; ++cf) bcur[cf] = bnxt[cf];
  }
  // ---- epilogue: bias, anchor-row writes, BN2 bins (LDS only) ----
  float b2v[4];
#pragma unroll
  for (int cf = 0; cf < 4; ++cf) b2v[cf] = b2[colBase + cf * 16 + li];
#pragma unroll
  for (int fr = 0; fr < 4; ++fr) {
#pragma unroll
    for (int reg = 0; reg < 4; ++reg) {
      int row = fr * 16 + lg * 4 + reg;
      bool valid = row < 50;
      int il = row / 10, jj = row - il * 10;
      float z0 = acc[fr][0][reg] + b2v[0];
      float z1 = acc[fr][1][reg] + b2v[1];
      float z2 = acc[fr][2][reg] + b2v[2];
      float z3 = acc[fr][3][reg] + b2v[3];
      if (valid && (i0 + il) == anc) {
        float* dst = Z2out + (b * 10 + jj) * 256 + colBase + li;
        dst[0] = z0; dst[16] = z1; dst[32] = z2; dst[48] = z3;
      }
      float s = valid ? (z0 + z1 + z2 + z3) : 0.f;
      float q = valid ? (z0 * z0 + z1 * z1 + z2 * z2 + z3 * z3) : 0.f;
#pragma unroll
      for (int o = 1; o < 16; o <<= 1) {
        s += __shfl_xor(s, o);
        q += __shfl_xor(q, o);
      }
      if (li == 0 && valid) {
        atomicAdd(&bins[il], s);
        atomicAdd(&bins[5 + il], q);
      }
    }
  }
  __syncthreads();
  if (t < 5) {
    Part2[(br * 10 + i0 + t) * 512 + b] = bins[t];
    Part2[10240 + (br * 10 + i0 + t) * 512 + b] = bins[5 + t];
  }
}

// ---------------- BN2 finalize: wave-parallel Part2 reduction ----------------
__global__ __launch_bounds__(256) void finalize_bn2(
    const float* __restrict__ Part2,
    const float* __restrict__ a_g2, const float* __restrict__ a_be2,
    const float* __restrict__ s_g2, const float* __restrict__ s_be2,
    float* __restrict__ ST) {
  int t = threadIdx.x;
  int w = t >> 6, l = t & 63;
#pragma unroll
  for (int pp = 0; pp < 5; ++pp) {
    int p = w * 5 + pp;  // p = br*10 + i
    float s = 0.f, q = 0.f;
#pragma unroll
    for (int k = 0; k < 8; ++k) {
      s += Part2[p * 512 + l + k * 64];
      q += Part2[10240 + p * 512 + l + k * 64];
    }
    s = wred64(s);
    q = wred64(q);
    if (l == 0) {
      int br = p / 10, i = p - br * 10;
      const float invN = 1.f / (512.f * 10.f * 256.f);
      float m = s * invN;
      float v = q * invN - m * m;
      float g = br ? s_g2[i] : a_g2[i];
      float be = br ? s_be2[i] : a_be2[i];
      float sc = g / sqrtf(v + 1e-5f);
      ST[144 + br * 20 + i] = sc;
      ST[144 + br * 20 + 10 + i] = be - m * sc;
    }
  }
}

// ---------------- generic MFMA GEMM (32-row tiles), for GRU ----------------
__global__ __launch_bounds__(256) void gemm_mfma(
    const unsigned short* __restrict__ A, const unsigned short* __restrict__ Bw,
    float* __restrict__ C, const float* __restrict__ bias, int K, int N) {
  int t = threadIdx.x;
  int w = t >> 6, l = t & 63, li = l & 15, lg = l >> 4;
  int rowBase = blockIdx.x * 32;
  int colBase = blockIdx.y * 256 + w * 64;
  f32x4 acc[2][4] = {};
  const unsigned short* Arow[2];
  const unsigned short* Brow[4];
#pragma unroll
  for (int fr = 0; fr < 2; ++fr) Arow[fr] = A + (rowBase + fr * 16 + li) * K;
#pragma unroll
  for (int cf = 0; cf < 4; ++cf) Brow[cf] = Bw + (colBase + cf * 16 + li) * K;
  for (int ks = 0; ks < K / 32; ++ks) {
    int ka = ks * 32 + lg * 8;
    short8 afr[2], bfr[4];
#pragma unroll
    for (int fr = 0; fr < 2; ++fr) afr[fr] = *(const short8*)&Arow[fr][ka];
#pragma unroll
    for (int cf = 0; cf < 4; ++cf) bfr[cf] = *(const short8*)&Brow[cf][ka];
#pragma unroll
    for (int fr = 0; fr < 2; ++fr)
#pragma unroll
      for (int cf = 0; cf < 4; ++cf)
        acc[fr][cf] = __builtin_amdgcn_mfma_f32_16x16x32_bf16(afr[fr], bfr[cf], acc[fr][cf], 0, 0, 0);
  }
  float b2v[4] = {0.f, 0.f, 0.f, 0.f};
  if (bias) {
#pragma unroll
    for (int cf = 0; cf < 4; ++cf) b2v[cf] = bias[colBase + cf * 16 + li];
  }
#pragma unroll
  for (int fr = 0; fr < 2; ++fr)
#pragma unroll
    for (int reg = 0; reg < 4; ++reg) {
      int r = rowBase + fr * 16 + lg * 4 + reg;
      float* crow = C + r * N + colBase + li;
#pragma unroll
      for (int cf = 0; cf < 4; ++cf) crow[cf * 16] = acc[fr][cf][reg] + b2v[cf];
    }
}

// ---------------- postproc ----------------
__global__ __launch_bounds__(256) void postproc_kernel(
    const float* __restrict__ Z2a, const float* __restrict__ Z2s, const float* __restrict__ ST,
    const float* __restrict__ a_w3, const float* __restrict__ a_b3,
    const float* __restrict__ mu_w, const float* __restrict__ mu_b,
    const float* __restrict__ sg_w, const float* __restrict__ sg_b,
    const float* __restrict__ aij_eps, const float* __restrict__ sij_eps,
    const int* __restrict__ cl, const float* __restrict__ utt,
    unsigned short* __restrict__ msgbf, unsigned short* __restrict__ h0bf,
    float* __restrict__ h0out) {
  int b = blockIdx.x, t = threadIdx.x;
  int a = cl[b] - 1;
  float sc2a = ST[144 + a], sh2a = ST[154 + a];
  float sc2s = ST[164 + a], sh2s = ST[174 + a];
  float w3 = a_w3[t], mw = mu_w[t], sw = sg_w[t];
  __shared__ float red[30];
  if (t < 30) red[t] = 0.f;
  __syncthreads();
#pragma unroll
  for (int j = 0; j < 10; ++j) {
    float za = Z2a[(b * 10 + j) * 256 + t];
    float va = fmaxf(za * sc2a + sh2a, 0.f);
    float zs = Z2s[(b * 10 + j) * 256 + t];
    float vs = tanhf(zs * sc2s + sh2s);
    float pa = wred64(va * w3);
    float pm = wred64(vs * mw);
    float ps = wred64(vs * sw);
    if ((t & 63) == 0) {
      atomicAdd(&red[j], pa);
      atomicAdd(&red[10 + j], pm);
      atomicAdd(&red[20 + j], ps);
    }
  }
  __syncthreads();
  __shared__ float pw[10];
  __shared__ float wijs[16];
  if (t < 10) {
    int j = t;
    float amij = red[j] + a_b3[0];
    float amu = softplusf(amij) + 0.01f;
    float astd = sqrtf(softplusf((1.f - amu) * amu) + 0.01f);
    float ae = aij_eps[b * 100 + a * 10 + j];
    float aij = softplusf(ae * astd + amu) + 0.01f;
    float smu = red[10 + j] + mu_b[0];
    float ssg = red[20 + j] + sg_b[0];
    float se = sij_eps[b * 100 + a * 10 + j];
    float sij = se * sqrtf(aij * ssg * ssg) + aij * smu;
    wijs[j] = aij * sij;
  }
  __syncthreads();
  if (t == 0) {
    float mx = -1e30f;
    for (int j = 0; j < a; ++j) mx = fmaxf(mx, wijs[j]);
    float e[10];
    float den = 0.f;
    for (int j = 0; j < a; ++j) { e[j] = expf(wijs[j] - mx); den += e[j]; }
    for (int j = 0; j < 10; ++j) pw[j] = (j < a) ? e[j] / den : 0.f;
  }
  __syncthreads();
#pragma unroll
  for (int dd = 0; dd < 2; ++dd) {
    int d = t + dd * 256;
    float mv = 0.f;
#pragma unroll
    for (int j = 0; j < 10; ++j) mv += pw[j] * utt[(b * 10 + j) * 512 + d];
    msgbf[b * 512 + d] = f2bf(mv);
  }
  float u1 = utt[(b * 10 + a) * 512 + t];
  float u2 = utt[(b * 10 + a) * 512 + 256 + t];
  float h0v = u1 + u2;
  h0out[b * 256 + t] = h0v;
  h0bf[b * 256 + t] = f2bf(h0v);
}

// ---------------- GRU elementwise ----------------
__global__ __launch_bounds__(256) void gru_final(const float* __restrict__ gi,
                                                 const float* __restrict__ gh,
                                                 const float* __restrict__ h0,
                                                 float* __restrict__ out) {
  int idx = blockIdx.x * 256 + threadIdx.x;
  int b = idx >> 8, h = idx & 255;
  float ir = gi[b * 768 + h], iz = gi[b * 768 + 256 + h], inn = gi[b * 768 + 512 + h];
  float hr = gh[b * 768 + h], hz = gh[b * 768 + 256 + h], hn = gh[b * 768 + 512 + h];
  float r = 1.f / (1.f + expf(-(ir + hr)));
  float z = 1.f / (1.f + expf(-(iz + hz)));
  float n = tanhf(inn + r * hn);
  out[idx] = (1.f - z) * n + z * h0[b * 256 + h];
}

extern "C" void kernel_launch(void* const* d_in, const int* in_sizes, int n_in,
                              void* d_out, int out_size, void* d_ws, size_t ws_size,
                              hipStream_t stream) {
  const float* utt = (const float*)d_in[0];
  const float* aij_eps = (const float*)d_in[1];
  const float* sij_eps = (const float*)d_in[2];
  const int* cl = (const int*)d_in[3];
  const float* a_w1 = (const float*)d_in[4];
  const float* a_b1 = (const float*)d_in[5];
  const float* a_g1 = (const float*)d_in[6];
  const float* a_be1 = (const float*)d_in[7];
  const float* a_w2 = (const float*)d_in[8];
  const float* a_b2 = (const float*)d_in[9];
  const float* a_g2 = (const float*)d_in[10];
  const float* a_be2 = (const float*)d_in[11];
  const float* a_w3 = (const float*)d_in[12];
  const float* a_b3 = (const float*)d_in[13];
  const float* s_w1 = (const float*)d_in[14];
  const float* s_b1 = (const float*)d_in[15];
  const float* s_g1 = (const float*)d_in[16];
  const float* s_be1 = (const float*)d_in[17];
  const float* s_w2 = (const float*)d_in[18];
  const float* s_b2 = (const float*)d_in[19];
  const float* s_g2 = (const float*)d_in[20];
  const float* s_be2 = (const float*)d_in[21];
  const float* mu_w = (const float*)d_in[22];
  const float* mu_b = (const float*)d_in[23];
  const float* sg_w = (const float*)d_in[24];
  const float* sg_b = (const float*)d_in[25];
  const float* gru_wi = (const float*)d_in[26];
  const float* gru_wh = (const float*)d_in[27];
  const float* gru_bi = (const float*)d_in[28];
  const float* gru_bh = (const float*)d_in[29];

  float* ws = (float*)d_ws;
  float* ST = ws;                                            // 256 floats
  unsigned short* Af = (unsigned short*)(ws + 256);          // 2621440 sh
  unsigned short* Bf = Af + 2621440;                         // 524288 sh
  unsigned short* W2fa = Bf + 524288;                        // 65536 sh
  unsigned short* W2fs = W2fa + 65536;                       // 65536 sh
  unsigned short* wibf = W2fs + 65536;                       // 393216 sh
  unsigned short* whbf = wibf + 393216;                      // 196608 sh
  float* PQf = (float*)(whbf + 196608);                      // region: 5242880 f (PQ bf16 uses half)
  unsigned short* PQ = (unsigned short*)PQf;                 // 5242880 sh used
  float* Z2a = PQf + 5242880;                                // 1310720 f
  float* Z2s = Z2a + 1310720;                                // 1310720 f
  float* Part = Z2s + 1310720;                               // 32768 f
  float* Part2 = Part + 32768;                               // 20480 f
  // postproc/GRU buffers alias the tail of the PQ region (PQ bf16 occupies first half only)
  float* tailf = PQf + 2621440;                              // 2621440 f free
  unsigned short* msgbf = (unsigned short*)tailf;            // 262144 sh
  unsigned short* h0bf = msgbf + 262144;                     // 131072 sh
  float* h0 = tailf + 196608;                                // 131072 f
  float* gi = tailf + 327680;                                // 393216 f
  float* gh = gi + 393216;                                   // 393216 f

  prep_weights<<<1024, 256, 0, stream>>>(utt, a_w1, s_w1, a_w2, s_w2, gru_wi, gru_wh,
                                         Af, Bf, W2fa, W2fs, wibf, whbf);
  gemm_pq_swz<<<dim3(160, 4), 256, 0, stream>>>(Af, Bf, PQ);
  stats_kernel<<<dim3(512, 2), 256, 0, stream>>>(PQ, a_b1, s_b1, Part);
  reduce_bn1<<<2, 256, 0, stream>>>(Part, a_b1, s_b1, a_g1, a_be1, s_g1, s_be1, ST);
  fused_layer2_half<<<dim3(512, 2, 2), 256, 0, stream>>>(PQ, ST, a_b1, s_b1, W2fa, W2fs,
                                                         a_b2, s_b2, cl, Z2a, Z2s, Part2);
  finalize_bn2<<<1, 256, 0, stream>>>(Part2, a_g2, a_be2, s_g2, s_be2, ST);
  postproc_kernel<<<512, 256, 0, stream>>>(Z2a, Z2s, ST, a_w3, a_b3, mu_w, mu_b, sg_w, sg_b,
                                           aij_eps, sij_eps, cl, utt, msgbf, h0bf, h0);
  gemm_mfma<<<dim3(16, 3), 256, 0, stream>>>(msgbf, wibf, gi, gru_bi, 512, 768);
  gemm_mfma<<<dim3(16, 3), 256, 0, stream>>>(h0bf, whbf, gh, gru_bh, 256, 768);
  gru_final<<<512, 256, 0, stream>>>(gi, gh, h0, (float*)d_out);
}